// Round 1
// baseline (223.510 us; speedup 1.0000x reference)
//
#include <hip/hip_runtime.h>
#include <hip/hip_bf16.h>

// Simple_6270652252303. Inputs float32 (detector-verified; bf16 path kept).
// sA constant (runtime-verified) => closed-form S6:
//   y[b,t,d] = E_t[d] * sum_{s<=t} G_b[t,s] * dx_s[d]/E_s[d]
//   G_b[t,s] = Z_t.T2_s + ru_t + rv_s + k0,  Z = T2@M33p (cols 100=u,101=v)
// R13: fuse k_G+k_Y+k_head into k_GYH at the same 512-block (b,tc) spread.
//   G stays in LDS (no global G / yT round-trips); V,E built by streaming
//   ddx with an on-the-fly prefix; head projection reduced in-wave and
//   written straight to d_out. Keeps per-CU LDS work spread (full 64-block
//   fusion would concentrate ~4x LDS traffic per CU - rejected).
// k_A (R12 structure) unchanged; k_B/k_scan/k_headF are gated fallbacks.

typedef __hip_bfloat16 bf16;

#define BATCH 64
#define SEQ   63
#define ROWS  (BATCH * SEQ)   // 4032
#define DIN   100
#define H1    128
#define DM    100
#define NS    300

__device__ __forceinline__ float2 up2(unsigned u) {
    float2 r;
    r.x = __uint_as_float(u << 16);
    r.y = __uint_as_float(u & 0xffff0000u);
    return r;
}
template<bool ISB>
__device__ __forceinline__ float LD(const void* p, int i) {
    if (ISB) return __bfloat162float(((const bf16*)p)[i]);
    else     return ((const float*)p)[i];
}
template<bool ISB>
__device__ __forceinline__ float2 LD2(const void* p, int i) {   // elems 2i,2i+1
    if (ISB) return up2(((const unsigned*)p)[i]);
    else     return ((const float2*)p)[i];
}
__device__ __forceinline__ float waveReduceSum(float v) {
#pragma unroll
    for (int off = 32; off > 0; off >>= 1) v += __shfl_xor(v, off, 64);
    return v;
}
__device__ __forceinline__ float4 waveReduceSum4(float4 v) {
#pragma unroll
    for (int off = 32; off > 0; off >>= 1) {
        const float a = __shfl_xor(v.x, off, 64);
        const float b = __shfl_xor(v.y, off, 64);
        const float c = __shfl_xor(v.z, off, 64);
        const float d = __shfl_xor(v.w, off, 64);
        v.x += a; v.y += b; v.z += c; v.w += d;
    }
    return v;
}
__device__ __forceinline__ float lrelu(float x) { return x >= 0.f ? x : 0.01f * x; }
__device__ __forceinline__ float softplusf(float x) {
    return (x > 20.f) ? x : log1pf(__expf(x));
}
__device__ __forceinline__ bool flags_uniform(const float* __restrict__ f) {
    bool u = true;
#pragma unroll
    for (int i = 0; i < 8; ++i) u &= (f[i] > 0.5f);
    return u;
}
__device__ __forceinline__ bool detect_bf16(const unsigned short* __restrict__ probe) {
    const int l = threadIdx.x & 63;
    const unsigned u0 = probe[l * 2];
    const unsigned u1 = probe[l * 2 + 1];
    const float v0 = fabsf(__uint_as_float(u0 << 16));
    const float v1 = fabsf(__uint_as_float(u1 << 16));
    const bool big = !(v0 < 1000.f) || !(v1 < 1000.f);
    const bool zero_even = (u0 == 0u);
    const unsigned long long mb = __ballot(big);
    const unsigned long long mz = __ballot(zero_even);
    return (mb == 0ULL) && (__popcll(mz) < 32);
}

// ---------------------------------------------------------------------------
// k_A: grid 613. Blocks 0..503: main row pipeline (8 rows/block, 2 rows/wave).
//   Weights staged in LDS per phase (tW1 -> tW2 -> sW1), block barriers
//   between phases; inner loops are pure VALU + ds_read (no global latency).
// Blocks 504..603: M33p row (d3 = blk-504) + u/v cols (+k0 on 504).
// Blocks 604..611: A-uniformity check. Block 612: collapsed head Mkv.
// ---------------------------------------------------------------------------
template<bool ISB>
__device__ __forceinline__ void a_main(
    const void* __restrict__ text,
    const void* __restrict__ tW1, const void* __restrict__ tb1,
    const void* __restrict__ tg1, const void* __restrict__ tbe1,
    const void* __restrict__ tW2, const void* __restrict__ tb2,
    const void* __restrict__ tg2, const void* __restrict__ tbe2,
    const void* __restrict__ sW1w, const void* __restrict__ sb1,
    float* __restrict__ ddx, float* __restrict__ t2g,
    float* __restrict__ sW,
    float (&xb)[4][DIN][2], float (&t1b)[4][H1][2], float (&t2b)[4][DM][2])
{
    const int tid  = threadIdx.x;
    const int w    = tid >> 6;
    const int lane = tid & 63;
    const int r0   = blockIdx.x * 8 + w * 2;

    if (lane < 50) {
#pragma unroll
        for (int r = 0; r < 2; ++r) {
            const float2 xv = LD2<ISB>(text, (r0 + r) * 50 + lane);
            xb[w][2 * lane][r]     = xv.x;
            xb[w][2 * lane + 1][r] = xv.y;
        }
    }
    // ---- stage tW1 (100x128 = 6400 float2) ----
    for (int i = tid; i < 6400; i += 256)
        *(float2*)&sW[2 * i] = LD2<ISB>(tW1, i);
    __syncthreads();

    // ---- GEMM1 (100 -> 128) from LDS ----
    const float2 b1v = LD2<ISB>(tb1, lane);
    float ax0 = b1v.x, ay0 = b1v.y, ax1 = b1v.x, ay1 = b1v.y;
#pragma unroll 10
    for (int k = 0; k < DIN; ++k) {
        const float2 wv = *(const float2*)&sW[k * 128 + 2 * lane];
        const float2 xv = *(const float2*)&xb[w][k][0];
        ax0 += xv.x * wv.x; ay0 += xv.x * wv.y;
        ax1 += xv.y * wv.x; ay1 += xv.y * wv.y;
    }
    {   // LN(128)+LReLU
        float4 red = waveReduceSum4(make_float4(
            ax0 + ay0, ax0 * ax0 + ay0 * ay0,
            ax1 + ay1, ax1 * ax1 + ay1 * ay1));
        const float m0 = red.x * (1.f / 128.f);
        const float rs0 = rsqrtf(red.y * (1.f / 128.f) - m0 * m0 + 1e-5f);
        const float m1 = red.z * (1.f / 128.f);
        const float rs1 = rsqrtf(red.w * (1.f / 128.f) - m1 * m1 + 1e-5f);
        const float2 g = LD2<ISB>(tg1, lane), be = LD2<ISB>(tbe1, lane);
        float2 v;
        v.x = lrelu((ax0 - m0) * rs0 * g.x + be.x);
        v.y = lrelu((ax1 - m1) * rs1 * g.x + be.x);
        *(float2*)&t1b[w][2 * lane][0] = v;
        v.x = lrelu((ay0 - m0) * rs0 * g.y + be.y);
        v.y = lrelu((ay1 - m1) * rs1 * g.y + be.y);
        *(float2*)&t1b[w][2 * lane + 1][0] = v;
    }
    __syncthreads();                 // all waves done with tW1

    // ---- stage tW2 (128x100 = 6400 float2) ----
    for (int i = tid; i < 6400; i += 256)
        *(float2*)&sW[2 * i] = LD2<ISB>(tW2, i);
    __syncthreads();

    // ---- GEMM2 (128 -> 100) from LDS ----
    const bool act = lane < 50;
    const int  li  = act ? lane : 0;
    const float2 b2v = LD2<ISB>(tb2, li);
    float cx0 = b2v.x, cy0 = b2v.y, cx1 = b2v.x, cy1 = b2v.y;
#pragma unroll 8
    for (int k = 0; k < H1; ++k) {
        const float2 wv = *(const float2*)&sW[k * 100 + 2 * li];
        const float2 tv = *(const float2*)&t1b[w][k][0];
        cx0 += tv.x * wv.x; cy0 += tv.x * wv.y;
        cx1 += tv.y * wv.x; cy1 += tv.y * wv.y;
    }
    float u0x, u0y, u1x, u1y;
    {   // LN(100)+LReLU -> t2b, t2g
        float4 red = waveReduceSum4(act ? make_float4(
            cx0 + cy0, cx0 * cx0 + cy0 * cy0,
            cx1 + cy1, cx1 * cx1 + cy1 * cy1) : make_float4(0.f, 0.f, 0.f, 0.f));
        const float m0 = red.x * 0.01f;
        const float rs0 = rsqrtf(red.y * 0.01f - m0 * m0 + 1e-5f);
        const float m1 = red.z * 0.01f;
        const float rs1 = rsqrtf(red.w * 0.01f - m1 * m1 + 1e-5f);
        if (act) {
            const float2 g = LD2<ISB>(tg2, lane), be = LD2<ISB>(tbe2, lane);
            u0x = lrelu((cx0 - m0) * rs0 * g.x + be.x);
            u0y = lrelu((cy0 - m0) * rs0 * g.y + be.y);
            u1x = lrelu((cx1 - m1) * rs1 * g.x + be.x);
            u1y = lrelu((cy1 - m1) * rs1 * g.y + be.y);
            t2b[w][2 * lane][0] = u0x; t2b[w][2 * lane + 1][0] = u0y;
            t2b[w][2 * lane][1] = u1x; t2b[w][2 * lane + 1][1] = u1y;
            *(float2*)(t2g + (r0)     * DM + 2 * lane) = make_float2(u0x, u0y);
            *(float2*)(t2g + (r0 + 1) * DM + 2 * lane) = make_float2(u1x, u1y);
        }
    }
    __syncthreads();                 // all waves done with tW2

    // ---- stage sW1 (100x100 = 5000 float2) ----
    for (int i = tid; i < 5000; i += 256)
        *(float2*)&sW[2 * i] = LD2<ISB>(sW1w, i);
    __syncthreads();

    // ---- delta (100 cols) from LDS -> ddx {de, de*t2} ----
    const float2 sbv = LD2<ISB>(sb1, li);
    float dA0x = sbv.x, dA0y = sbv.y, dA1x = sbv.x, dA1y = sbv.y;
#pragma unroll 10
    for (int k = 0; k < DM; ++k) {
        const float2 wv = *(const float2*)&sW[k * 100 + 2 * li];
        const float2 tv = *(const float2*)&t2b[w][k][0];
        dA0x += tv.x * wv.x; dA0y += tv.x * wv.y;
        dA1x += tv.y * wv.x; dA1y += tv.y * wv.y;
    }
    if (act) {
        float de0 = softplusf(dA0x), de1 = softplusf(dA0y);
        float4 o;
        o.x = de0; o.y = de0 * u0x; o.z = de1; o.w = de1 * u0y;
        *(float4*)(ddx + (r0) * (2 * DM) + 4 * lane) = o;
        de0 = softplusf(dA1x); de1 = softplusf(dA1y);
        o.x = de0; o.y = de0 * u1x; o.z = de1; o.w = de1 * u1y;
        *(float4*)(ddx + (r0 + 1) * (2 * DM) + 4 * lane) = o;
    }
}

// prep duty: M33p row d3 (+ u,v cols; k0 on d3==0). Uses sW[0..943] as scratch.
template<bool ISB>
__device__ __forceinline__ void a_prep(
    const void* __restrict__ sW2, const void* __restrict__ sb2,
    const void* __restrict__ sW3, const void* __restrict__ sb3,
    float* __restrict__ M33p, float* __restrict__ k0w, float* __restrict__ sW,
    int d3)
{
    const int tid = threadIdx.x;
    const int w = tid >> 6, lane = tid & 63;
    float* W3row = sW;          // 300
    float* b2v   = sW + 320;    // 300
    float* b3v   = sW + 640;    // 300
    for (int i = tid; i < 300; i += 256) {
        W3row[i] = LD<ISB>(sW3, d3 * 300 + i);
        b2v[i]   = LD<ISB>(sb2, i);
        b3v[i]   = LD<ISB>(sb3, i);
    }
    __syncthreads();
    // wave w: d2 rows {w*25 .. w*25+24}, groups of 4 (6 groups + 1 leftover)
    for (int g = 0; g < 6; ++g) {
        const int d2 = w * 25 + g * 4;
        float4 p = make_float4(0.f, 0.f, 0.f, 0.f);
#pragma unroll
        for (int rep = 0; rep < 5; ++rep) {
            const int n = lane + 64 * rep;
            if (n < 300) {
                const float w3 = W3row[n];
                p.x += LD<ISB>(sW2, (d2 + 0) * 300 + n) * w3;
                p.y += LD<ISB>(sW2, (d2 + 1) * 300 + n) * w3;
                p.z += LD<ISB>(sW2, (d2 + 2) * 300 + n) * w3;
                p.w += LD<ISB>(sW2, (d2 + 3) * 300 + n) * w3;
            }
        }
        p = waveReduceSum4(p);
        if (lane == 0) {
            M33p[d3 * 102 + d2 + 0] = p.x;
            M33p[d3 * 102 + d2 + 1] = p.y;
            M33p[d3 * 102 + d2 + 2] = p.z;
            M33p[d3 * 102 + d2 + 3] = p.w;
        }
    }
    {   // leftover row d2 = w*25+24, plus u (w0), v (w1), k0 (w2, d3==0)
        const int d2 = w * 25 + 24;
        float4 p = make_float4(0.f, 0.f, 0.f, 0.f);
#pragma unroll
        for (int rep = 0; rep < 5; ++rep) {
            const int n = lane + 64 * rep;
            if (n < 300) {
                p.x += LD<ISB>(sW2, d2 * 300 + n) * W3row[n];
                if (w == 0) p.y += W3row[n] * b2v[n];                       // u[d3]
                if (w == 1) p.y += LD<ISB>(sW2, d3 * 300 + n) * b3v[n];     // v[d3]
                if (w == 2 && d3 == 0) p.y += b2v[n] * b3v[n];              // k0
            }
        }
        p = waveReduceSum4(p);
        if (lane == 0) {
            M33p[d3 * 102 + d2] = p.x;
            if (w == 0) M33p[d3 * 102 + 100] = p.y;
            if (w == 1) M33p[d3 * 102 + 101] = p.y;
            if (w == 2 && d3 == 0) k0w[0] = p.y;
        }
    }
}

template<bool ISB>
__device__ __forceinline__ void a_check(
    const void* __restrict__ sA, float* __restrict__ Afl,
    float* __restrict__ sW, int j)
{
    const int tid = threadIdx.x;
    const float a0 = LD<ISB>(sA, 0);
    bool ok = true;
    for (int i = j * 3750 + tid; i < (j + 1) * 3750; i += 256)
        ok &= (LD<ISB>(sA, i) == a0);
    if (tid == 0) sW[960] = 1.f;
    __syncthreads();
    if (!ok) sW[960] = 0.f;          // benign same-value race
    __syncthreads();
    if (tid == 0) Afl[j] = sW[960];
    if (j == 0 && tid == 1) Afl[8] = a0;
}

template<bool ISB>
__device__ __forceinline__ void a_mkv(
    const void* __restrict__ cW1, const void* __restrict__ cb1,
    const void* __restrict__ cW2, const void* __restrict__ cb2,
    float* __restrict__ Mkv)
{
    const int t = threadIdx.x;
    if (t < 200) {
        const int d = t >> 1, j = t & 1;
        float m = 0.f;
#pragma unroll 5
        for (int i = 0; i < 50; ++i)
            m += LD<ISB>(cW1, d * 50 + i) * LD<ISB>(cW2, 2 * i + j);
        Mkv[t] = m;
    } else if (t < 202) {
        const int j = t - 200;
        float kv = LD<ISB>(cb2, j);
#pragma unroll 5
        for (int i = 0; i < 50; ++i)
            kv += LD<ISB>(cb1, i) * LD<ISB>(cW2, 2 * i + j);
        Mkv[200 + j] = kv;
    }
}

__global__ __launch_bounds__(256) void k_A(
    const void* text,
    const void* tW1, const void* tb1, const void* tg1, const void* tbe1,
    const void* tW2, const void* tb2, const void* tg2, const void* tbe2,
    const void* sW1w, const void* sb1,
    const void* sW2, const void* sb2, const void* sW3, const void* sb3,
    const void* sA,
    const void* cW1, const void* cb1, const void* cW2, const void* cb2,
    float* ddx, float* t2g, float* Mkv, float* M33p, float* k0w, float* Afl,
    const unsigned short* probe)
{
    __shared__ __align__(16) float sW[12800];       // 51.2 KB (phase weights)
    __shared__ __align__(16) float xb[4][DIN][2];
    __shared__ __align__(16) float t1b[4][H1][2];
    __shared__ __align__(16) float t2b[4][DM][2];
    const bool isb = detect_bf16(probe);
    const int blk = blockIdx.x;
    if (blk < 504) {
        if (isb) a_main<true >(text, tW1, tb1, tg1, tbe1, tW2, tb2, tg2, tbe2,
                               sW1w, sb1, ddx, t2g, sW, xb, t1b, t2b);
        else     a_main<false>(text, tW1, tb1, tg1, tbe1, tW2, tb2, tg2, tbe2,
                               sW1w, sb1, ddx, t2g, sW, xb, t1b, t2b);
    } else if (blk < 604) {
        if (isb) a_prep<true >(sW2, sb2, sW3, sb3, M33p, k0w, sW, blk - 504);
        else     a_prep<false>(sW2, sb2, sW3, sb3, M33p, k0w, sW, blk - 504);
    } else if (blk < 612) {
        if (isb) a_check<true >(sA, Afl, sW, blk - 604);
        else     a_check<false>(sA, Afl, sW, blk - 604);
    } else {
        if (isb) a_mkv<true >(cW1, cb1, cW2, cb2, Mkv);
        else     a_mkv<false>(cW1, cb1, cW2, cb2, Mkv);
    }
}

// ---------------------------------------------------------------------------
// k_GYH (fast path): grid 512 = (batch, t-chunk of 8). Fuses G + Y + head.
//   G[t,s] = k0 + Z[t][100] + rv_s + sum_k Z[t][k]*T2[s][k]   (LDS only)
//   V[d][s] = num[s,d]/E[s,d],  E[t,d] = exp(a * prefix(de)),  streamed
//   y[t,d] = E[t,d] * sum_{s<=t} G[t,s] V[d,s];  out = y@Mkv + kv  (in-wave)
// ---------------------------------------------------------------------------
template<bool ISB>
__device__ __forceinline__ void gyh_impl(
    const float* __restrict__ t2g, const float* __restrict__ ddx,
    const float* __restrict__ M33p, const float* __restrict__ k0w,
    const float* __restrict__ Mkv, const float* __restrict__ Afl,
    void* __restrict__ outp,
    float* __restrict__ sT2, float (&sZ)[8][104],
    float* __restrict__ sv, float* __restrict__ srv,
    float (&sG)[8][64], float* __restrict__ sV, float (&sE)[8][100])
{
    const int b  = blockIdx.x >> 3;
    const int tc = blockIdx.x & 7;
    const int tid = threadIdx.x;
    const int w = tid >> 6, lane = tid & 63;

    // ---- stage T2 (whole batch) ----
    for (int i = tid; i < 3150; i += 256) {
        const float2 v = *(const float2*)(t2g + b * 6300 + 2 * i);
        const int t = i / 50, k = 2 * (i % 50);
        sT2[t * 102 + k]     = v.x;
        sT2[t * 102 + k + 1] = v.y;
    }
    if (tid < 100) sv[tid] = M33p[tid * 102 + 101];
    __syncthreads();

    if (lane < 16) {                 // rv[s], 16 s per wave
        const int s = w * 16 + lane;
        if (s < SEQ) {
            float acc = 0.f;
#pragma unroll 4
            for (int k = 0; k < 100; ++k) acc += sT2[s * 102 + k] * sv[k];
            srv[s] = acc;
        }
    }

    {   // Z rows (2 per wave) via one ring-prefetched M33p stream
        const int l2 = (lane < 51) ? 2 * lane : 0;
        int tg2i[2];
#pragma unroll
        for (int r = 0; r < 2; ++r) {
            const int t = tc * 8 + w * 2 + r;
            tg2i[r] = (t < SEQ) ? t : SEQ - 1;
        }
        float2 acc[2];
        acc[0] = make_float2(0.f, 0.f);
        acc[1] = make_float2(0.f, 0.f);
        float2 ring[10];
#pragma unroll
        for (int j = 0; j < 10; ++j) ring[j] = *(const float2*)(M33p + j * 102 + l2);
        for (int kk = 0; kk < 100; kk += 10) {
#pragma unroll
            for (int j = 0; j < 10; ++j) {
                const int jj = kk + j;
                const float2 wv = ring[j];
                if (jj + 10 < 100) ring[j] = *(const float2*)(M33p + (jj + 10) * 102 + l2);
#pragma unroll
                for (int r = 0; r < 2; ++r) {
                    const float tv = sT2[tg2i[r] * 102 + jj];
                    acc[r].x += tv * wv.x;
                    acc[r].y += tv * wv.y;
                }
            }
        }
        if (lane < 51) {
#pragma unroll
            for (int r = 0; r < 2; ++r)
                *(float2*)&sZ[w * 2 + r][l2] = acc[r];
        }
    }
    __syncthreads();

    {   // ---- G rows (2 per wave), kept in LDS; tv shared across both rows
        const float kz = k0w[0];
        const int s = lane;
        const int sc = (s < SEQ) ? s : SEQ - 1;
        float acc0 = kz + sZ[w * 2][100]     + srv[sc];
        float acc1 = kz + sZ[w * 2 + 1][100] + srv[sc];
#pragma unroll 5
        for (int k2 = 0; k2 < 50; ++k2) {
            const float2 tv = *(const float2*)&sT2[sc * 102 + 2 * k2];
            const float2 z0 = *(const float2*)&sZ[w * 2][2 * k2];
            const float2 z1 = *(const float2*)&sZ[w * 2 + 1][2 * k2];
            acc0 += z0.x * tv.x + z0.y * tv.y;
            acc1 += z1.x * tv.x + z1.y * tv.y;
        }
        if (s < SEQ) {
            if (tc * 8 + w * 2     < SEQ) sG[w * 2][s]     = acc0;
            if (tc * 8 + w * 2 + 1 < SEQ) sG[w * 2 + 1][s] = acc1;
        }
    }
    __syncthreads();

    {   // ---- V / E stream: thread d in [0,100), prefix over s ----
        const float a = Afl[8];
        const int tmax = (tc * 8 + 7 < SEQ) ? tc * 8 + 7 : SEQ - 1;
        if (tid < 100) {
            const int d = tid;
            float D = 0.f;
            for (int s = 0; s <= tmax; ++s) {
                const float2 dn = *(const float2*)(ddx + (b * SEQ + s) * 200 + 2 * d);
                D += dn.x;                       // de
                const float E = __expf(a * D);
                sV[d * 65 + s] = dn.y / E;       // num / E
                const int tl = s - tc * 8;
                if (tl >= 0) sE[tl][d] = E;
            }
        }
    }
    __syncthreads();

    {   // ---- Y + head (2 t-rows per wave; in-wave reduce over d) ----
        const int li = (lane < 50) ? lane : 49;
        const float4 mk = *(const float4*)(Mkv + 4 * li);   // M[2li][0..1], M[2li+1][0..1]
        float4 oacc = make_float4(0.f, 0.f, 0.f, 0.f);
#pragma unroll
        for (int r = 0; r < 2; ++r) {
            const int tl = w * 2 + r;
            const int t  = tc * 8 + tl;
            if (t >= SEQ) continue;
            float acc0 = 0.f, acc1 = 0.f;
            const float* v0 = sV + (2 * li) * 65;
            const float* v1 = sV + (2 * li + 1) * 65;
            for (int s = 0; s <= t; ++s) {
                const float g = sG[tl][s];
                acc0 += g * v0[s];
                acc1 += g * v1[s];
            }
            const float2 E = *(const float2*)&sE[tl][2 * li];
            const float y0 = (lane < 50) ? E.x * acc0 : 0.f;
            const float y1 = (lane < 50) ? E.y * acc1 : 0.f;
            if (r == 0) { oacc.x = y0 * mk.x + y1 * mk.z; oacc.y = y0 * mk.y + y1 * mk.w; }
            else        { oacc.z = y0 * mk.x + y1 * mk.z; oacc.w = y0 * mk.y + y1 * mk.w; }
        }
        oacc = waveReduceSum4(oacc);
        if (lane == 0) {
            const float kv0 = Mkv[200], kv1 = Mkv[201];
#pragma unroll
            for (int r = 0; r < 2; ++r) {
                const int t = tc * 8 + w * 2 + r;
                if (t >= SEQ) continue;
                const int row = b * SEQ + t;
                const float o0 = (r == 0 ? oacc.x : oacc.z) + kv0;
                const float o1 = (r == 0 ? oacc.y : oacc.w) + kv1;
                if (ISB) {
                    ((bf16*)outp)[row * 2 + 0] = __float2bfloat16(o0);
                    ((bf16*)outp)[row * 2 + 1] = __float2bfloat16(o1);
                } else {
                    *(float2*)((float*)outp + row * 2) = make_float2(o0, o1);
                }
            }
        }
    }
}

__global__ __launch_bounds__(256) void k_GYH(
    const float* __restrict__ t2g, const float* __restrict__ ddx,
    const float* __restrict__ M33p, const float* __restrict__ k0w,
    const float* __restrict__ Mkv, const float* __restrict__ Afl,
    void* __restrict__ outp, const unsigned short* __restrict__ probe)
{
    __shared__ __align__(16) float sT2[64 * 102];
    __shared__ __align__(16) float sZ[8][104];
    __shared__ float sv[100];
    __shared__ float srv[64];
    __shared__ __align__(16) float sG[8][64];
    __shared__ __align__(16) float sV[100 * 65];
    __shared__ __align__(16) float sE[8][100];
    if (!flags_uniform(Afl)) return;
    if (detect_bf16(probe))
        gyh_impl<true >(t2g, ddx, M33p, k0w, Mkv, Afl, outp, sT2, sZ, sv, srv, sG, sV, sE);
    else
        gyh_impl<false>(t2g, ddx, M33p, k0w, Mkv, Afl, outp, sT2, sZ, sv, srv, sG, sV, sE);
}

// ---------------------------------------------------------------------------
// Fallback kernels (gated off when A uniform): R9 k_B + k_scan (row-major y).
// ---------------------------------------------------------------------------
template<bool ISB>
__device__ __forceinline__ float4 LD4(const void* p, int i) {
    if (ISB) {
        const uint2 u = ((const uint2*)p)[i];
        float4 r;
        r.x = __uint_as_float(u.x << 16);
        r.y = __uint_as_float(u.x & 0xffff0000u);
        r.z = __uint_as_float(u.y << 16);
        r.w = __uint_as_float(u.y & 0xffff0000u);
        return r;
    } else return ((const float4*)p)[i];
}

template<bool ISB>
__device__ __forceinline__ void b_impl(
    const float* __restrict__ t2g,
    const void* __restrict__ sW2, const void* __restrict__ sb2,
    const void* __restrict__ sW3, const void* __restrict__ sb3,
    float* __restrict__ BC, float (&sT)[DM][8])
{
    const int t  = threadIdx.x;
    const int r0 = blockIdx.x * 8;
    if (t < DM) {
#pragma unroll
        for (int r = 0; r < 8; ++r) sT[t][r] = t2g[(r0 + r) * DM + t];
    }
    __syncthreads();
    const bool isB = t < 75;
    const bool valid = t < 150;
    const int colbase = isB ? 4 * t : (valid ? 4 * (t - 75) : 0);
    const void* Wp   = isB ? sW2 : sW3;
    const void* bias = isB ? sb2 : sb3;
    const int rs4 = NS >> 2;
    const int cb4 = colbase >> 2;
    float4 acc[8];
    {
        const float4 bv = LD4<ISB>(bias, cb4);
#pragma unroll
        for (int r = 0; r < 8; ++r) acc[r] = bv;
    }
    float4 ring[4];
#pragma unroll
    for (int j = 0; j < 4; ++j) ring[j] = LD4<ISB>(Wp, j * rs4 + cb4);
    for (int kk = 0; kk < DM; kk += 4) {
#pragma unroll
        for (int j = 0; j < 4; ++j) {
            const int k = kk + j;
            const float4 wv = ring[j];
            if (k + 4 < DM) ring[j] = LD4<ISB>(Wp, (k + 4) * rs4 + cb4);
            const float4 lo = *(const float4*)&sT[k][0];
            const float4 hi = *(const float4*)&sT[k][4];
            acc[0].x += lo.x * wv.x; acc[0].y += lo.x * wv.y; acc[0].z += lo.x * wv.z; acc[0].w += lo.x * wv.w;
            acc[1].x += lo.y * wv.x; acc[1].y += lo.y * wv.y; acc[1].z += lo.y * wv.z; acc[1].w += lo.y * wv.w;
            acc[2].x += lo.z * wv.x; acc[2].y += lo.z * wv.y; acc[2].z += lo.z * wv.z; acc[2].w += lo.z * wv.w;
            acc[3].x += lo.w * wv.x; acc[3].y += lo.w * wv.y; acc[3].z += lo.w * wv.z; acc[3].w += lo.w * wv.w;
            acc[4].x += hi.x * wv.x; acc[4].y += hi.x * wv.y; acc[4].z += hi.x * wv.z; acc[4].w += hi.x * wv.w;
            acc[5].x += hi.y * wv.x; acc[5].y += hi.y * wv.y; acc[5].z += hi.y * wv.z; acc[5].w += hi.y * wv.w;
            acc[6].x += hi.z * wv.x; acc[6].y += hi.z * wv.y; acc[6].z += hi.z * wv.z; acc[6].w += hi.z * wv.w;
            acc[7].x += hi.w * wv.x; acc[7].y += hi.w * wv.y; acc[7].z += hi.w * wv.z; acc[7].w += hi.w * wv.w;
        }
    }
    if (valid) {
        const int off = isB ? 0 : 1;
#pragma unroll
        for (int r = 0; r < 8; ++r) {
            float* bp = BC + (r0 + r) * (2 * NS) + 2 * colbase + off;
            bp[0] = acc[r].x; bp[2] = acc[r].y;
            bp[4] = acc[r].z; bp[6] = acc[r].w;
        }
    }
}

__global__ __launch_bounds__(192, 1) void k_B(
    const float* t2g, const void* sW2, const void* sb2,
    const void* sW3, const void* sb3, float* BC,
    const float* Afl, const unsigned short* probe)
{
    __shared__ __align__(16) float sT[DM][8];
    if (flags_uniform(Afl)) return;
    if (detect_bf16(probe)) b_impl<true >(t2g, sW2, sb2, sW3, sb3, BC, sT);
    else                    b_impl<false>(t2g, sW2, sb2, sW3, sb3, BC, sT);
}

template<bool ISB>
__device__ __forceinline__ void scan_impl(
    const float* __restrict__ ddx, const float* __restrict__ BC,
    const void* __restrict__ sA, float* __restrict__ y,
    float (&sacc)[4][16][2][68])
{
    const int w    = threadIdx.x >> 6;
    const int lane = threadIdx.x & 63;
    const int wid  = blockIdx.x * 4 + w;
    const int b    = wid / 50;
    const int dp   = wid % 50;
    const int d0   = 2 * dp, d1 = d0 + 1;

    int nc[5]; bool nv[5];
    float A0[5], A1[5], h0[5], h1[5];
#pragma unroll
    for (int c = 0; c < 5; ++c) {
        const int n = lane + 64 * c;
        nv[c] = n < NS;
        nc[c] = nv[c] ? n : 0;
        A0[c] = nv[c] ? LD<ISB>(sA, d0 * NS + nc[c]) : 0.f;
        A1[c] = nv[c] ? LD<ISB>(sA, d1 * NS + nc[c]) : 0.f;
        h0[c] = 0.f; h1[c] = 0.f;
    }
    const float* ddp = ddx + (b * SEQ) * (2 * DM) + 4 * dp;
    const float* BCp = BC  + (b * SEQ) * (2 * NS);
    float*       yp  = y   + (b * SEQ) * DM + d0;

    float4 pdd[3];
    float2 pbc[3][5];
#pragma unroll
    for (int j = 0; j < 3; ++j) {
        pdd[j] = *(const float4*)(ddp + j * (2 * DM));
#pragma unroll
        for (int c = 0; c < 5; ++c)
            pbc[j][c] = nv[c] ? *(const float2*)(BCp + j * (2 * NS) + 2 * nc[c])
                              : make_float2(0.f, 0.f);
    }
    const int pr = lane >> 1;
    const int hh = lane & 1;
    const int sa = pr & 15;
    const int aa = pr >> 4;

#pragma unroll 3
    for (int l = 0; l < SEQ; ++l) {
        const int bi = l % 3;
        const float4 dd = pdd[bi];
        float2 bc[5];
#pragma unroll
        for (int c = 0; c < 5; ++c) bc[c] = pbc[bi][c];
        if (l + 3 < SEQ) {
            pdd[bi] = *(const float4*)(ddp + (l + 3) * (2 * DM));
#pragma unroll
            for (int c = 0; c < 5; ++c)
                pbc[bi][c] = nv[c] ? *(const float2*)(BCp + (l + 3) * (2 * NS) + 2 * nc[c])
                                   : make_float2(0.f, 0.f);
        }
        float a0 = 0.f, a1 = 0.f;
#pragma unroll
        for (int c = 0; c < 5; ++c) {
            h0[c] = __expf(dd.x * A0[c]) * h0[c] + dd.y * bc[c].x;
            a0 += bc[c].y * h0[c];
            h1[c] = __expf(dd.z * A1[c]) * h1[c] + dd.w * bc[c].x;
            a1 += bc[c].y * h1[c];
        }
        const int s = l & 15;
        sacc[w][s][0][lane] = a0;
        sacc[w][s][1][lane] = a1;

        if (s == 15 || l == SEQ - 1) {
            const int l0 = l & ~15;
            const int cs = l - l0 + 1;
            float sum = 0.f;
            if (sa < cs) {
                const float* rowp = &sacc[w][sa][aa][hh * 32];
#pragma unroll
                for (int i = 0; i < 8; ++i) {
                    const float4 v = *(const float4*)(rowp + 4 * i);
                    sum += v.x + v.y + v.z + v.w;
                }
            }
            sum += __shfl_xor(sum, 1, 64);
            if (hh == 0 && sa < cs) yp[(l0 + sa) * DM + aa] = sum;
        }
    }
}

__global__ __launch_bounds__(256) void k_scan(
    const float* ddx, const float* BC, const void* sA, float* y,
    const float* Afl, const unsigned short* probe)
{
    __shared__ __align__(16) float sacc[4][16][2][68];
    if (flags_uniform(Afl)) return;
    if (detect_bf16(probe)) scan_impl<true >(ddx, BC, sA, y, sacc);
    else                    scan_impl<false>(ddx, BC, sA, y, sacc);
}

// ---------------------------------------------------------------------------
// k_headF: FALLBACK-only head. out[row] = y[row] @ M + k, row-major y.
// ---------------------------------------------------------------------------
template<bool ISB>
__device__ __forceinline__ void headf_impl(
    const float* __restrict__ y, const float* __restrict__ Mkv,
    void* __restrict__ outp)
{
    const int row = blockIdx.x * 256 + threadIdx.x;
    if (row >= ROWS) return;
    float a0 = Mkv[200], a1 = Mkv[201];
    const float* yr = y + row * DM;
#pragma unroll 4
    for (int k = 0; k < DM; ++k) {
        const float v = yr[k];
        const float2 m = *(const float2*)(Mkv + 2 * k);
        a0 += v * m.x;
        a1 += v * m.y;
    }
    if (ISB) {
        ((bf16*)outp)[row * 2 + 0] = __float2bfloat16(a0);
        ((bf16*)outp)[row * 2 + 1] = __float2bfloat16(a1);
    } else {
        *(float2*)((float*)outp + row * 2) = make_float2(a0, a1);
    }
}

__global__ __launch_bounds__(256) void k_headF(
    const float* y, const float* Mkv, void* outp,
    const float* Afl, const unsigned short* probe)
{
    if (flags_uniform(Afl)) return;
    if (detect_bf16(probe)) headf_impl<true >(y, Mkv, outp);
    else                    headf_impl<false>(y, Mkv, outp);
}

// ---------------------------------------------------------------------------
extern "C" void kernel_launch(void* const* d_in, const int* in_sizes, int n_in,
                              void* d_out, int out_size, void* d_ws, size_t ws_size,
                              hipStream_t stream)
{
    const void* text = d_in[0];
    const void* tW1  = d_in[3];
    const void* tb1  = d_in[4];
    const void* tg1  = d_in[5];
    const void* tbe1 = d_in[6];
    const void* tW2  = d_in[7];
    const void* tb2  = d_in[8];
    const void* tg2  = d_in[9];
    const void* tbe2 = d_in[10];
    const void* sW1  = d_in[11];
    const void* sb1  = d_in[12];
    const void* sW2  = d_in[13];
    const void* sb2  = d_in[14];
    const void* sW3  = d_in[15];
    const void* sb3  = d_in[16];
    const void* sA   = d_in[17];
    const void* cW1  = d_in[34];
    const void* cb1  = d_in[35];
    const void* cW2  = d_in[36];
    const void* cb2  = d_in[37];
    const unsigned short* probe = (const unsigned short*)d_in[3];

    float* ws   = (float*)d_ws;
    float* ddx  = ws;                         // ROWS*200
    float* BCv  = ddx + ROWS * 2 * DM;        // ROWS*600 (fallback BC)
    float* yv   = BCv + ROWS * 2 * NS;        // ROWS*100 (t2g; fallback y)
    float* Mkv  = yv + ROWS * DM;             // 202
    float* M33p = Mkv + 202;                  // 100*102
    float* k0w  = M33p + 10200;               // 1
    float* Afl  = k0w + 1;                    // 9 (8 flags + a)
    float* t2g  = yv;                         // alias: consumed before y write

    k_A<<<613, 256, 0, stream>>>(
        text, tW1, tb1, tg1, tbe1, tW2, tb2, tg2, tbe2,
        sW1, sb1, sW2, sb2, sW3, sb3, sA,
        cW1, cb1, cW2, cb2,
        ddx, t2g, Mkv, M33p, k0w, Afl, probe);

    // Fast path: one fused kernel, G/V/E/Y/head all in LDS, writes d_out.
    k_GYH<<<BATCH * 8, 256, 0, stream>>>(t2g, ddx, M33p, k0w, Mkv, Afl,
                                         d_out, probe);

    // Fallback path (gated off when A uniform):
    k_B<<<ROWS / 8, 192, 0, stream>>>(t2g, sW2, sb2, sW3, sb3, BCv, Afl, probe);
    k_scan<<<3200 / 4, 256, 0, stream>>>(ddx, BCv, sA, yv, Afl, probe);
    k_headF<<<(ROWS + 255) / 256, 256, 0, stream>>>(yv, Mkv, d_out, Afl, probe);
}

// Round 2
// 192.595 us; speedup vs baseline: 1.1605x; 1.1605x over previous
//
#include <hip/hip_runtime.h>
#include <hip/hip_bf16.h>

// Simple_6270652252303. Inputs float32 (detector-verified; bf16 path kept).
// sA constant (runtime-verified) => closed-form S6:
//   y[b,t,d] = E_t[d] * sum_{s<=t} G_b[t,s] * dx_s[d]/E_s[d]
//   G_b[t,s] = Z_t.T2_s + ru_t + rv_s + k0,  Z = T2@M33p (cols 100=u,101=v)
// R14: fix R13's fused k_GYH (67us, 7.5% occupancy):
//   (a) sV aliases sT2 (dead after G phase) -> LDS 60->34.5KB;
//       __launch_bounds__(256,4) caps VGPR<=128 -> 4 blocks/CU (was 2 via
//       both LDS and the 132-VGPR cliff).
//   (b) XCD swizzle: all 8 tc-blocks of a batch share blockIdx%8 -> same
//       XCD L2 -> t2g/ddx/M33p re-reads become L2 hits (were 8x HBM fetch
//       round-robined across XCDs).
// k_A (R12 structure) unchanged; k_B/k_scan/k_headF are gated fallbacks.

typedef __hip_bfloat16 bf16;

#define BATCH 64
#define SEQ   63
#define ROWS  (BATCH * SEQ)   // 4032
#define DIN   100
#define H1    128
#define DM    100
#define NS    300

__device__ __forceinline__ float2 up2(unsigned u) {
    float2 r;
    r.x = __uint_as_float(u << 16);
    r.y = __uint_as_float(u & 0xffff0000u);
    return r;
}
template<bool ISB>
__device__ __forceinline__ float LD(const void* p, int i) {
    if (ISB) return __bfloat162float(((const bf16*)p)[i]);
    else     return ((const float*)p)[i];
}
template<bool ISB>
__device__ __forceinline__ float2 LD2(const void* p, int i) {   // elems 2i,2i+1
    if (ISB) return up2(((const unsigned*)p)[i]);
    else     return ((const float2*)p)[i];
}
__device__ __forceinline__ float waveReduceSum(float v) {
#pragma unroll
    for (int off = 32; off > 0; off >>= 1) v += __shfl_xor(v, off, 64);
    return v;
}
__device__ __forceinline__ float4 waveReduceSum4(float4 v) {
#pragma unroll
    for (int off = 32; off > 0; off >>= 1) {
        const float a = __shfl_xor(v.x, off, 64);
        const float b = __shfl_xor(v.y, off, 64);
        const float c = __shfl_xor(v.z, off, 64);
        const float d = __shfl_xor(v.w, off, 64);
        v.x += a; v.y += b; v.z += c; v.w += d;
    }
    return v;
}
__device__ __forceinline__ float lrelu(float x) { return x >= 0.f ? x : 0.01f * x; }
__device__ __forceinline__ float softplusf(float x) {
    return (x > 20.f) ? x : log1pf(__expf(x));
}
__device__ __forceinline__ bool flags_uniform(const float* __restrict__ f) {
    bool u = true;
#pragma unroll
    for (int i = 0; i < 8; ++i) u &= (f[i] > 0.5f);
    return u;
}
__device__ __forceinline__ bool detect_bf16(const unsigned short* __restrict__ probe) {
    const int l = threadIdx.x & 63;
    const unsigned u0 = probe[l * 2];
    const unsigned u1 = probe[l * 2 + 1];
    const float v0 = fabsf(__uint_as_float(u0 << 16));
    const float v1 = fabsf(__uint_as_float(u1 << 16));
    const bool big = !(v0 < 1000.f) || !(v1 < 1000.f);
    const bool zero_even = (u0 == 0u);
    const unsigned long long mb = __ballot(big);
    const unsigned long long mz = __ballot(zero_even);
    return (mb == 0ULL) && (__popcll(mz) < 32);
}

// ---------------------------------------------------------------------------
// k_A: grid 613. Blocks 0..503: main row pipeline (8 rows/block, 2 rows/wave).
//   Weights staged in LDS per phase (tW1 -> tW2 -> sW1), block barriers
//   between phases; inner loops are pure VALU + ds_read (no global latency).
// Blocks 504..603: M33p row (d3 = blk-504) + u/v cols (+k0 on 504).
// Blocks 604..611: A-uniformity check. Block 612: collapsed head Mkv.
// ---------------------------------------------------------------------------
template<bool ISB>
__device__ __forceinline__ void a_main(
    const void* __restrict__ text,
    const void* __restrict__ tW1, const void* __restrict__ tb1,
    const void* __restrict__ tg1, const void* __restrict__ tbe1,
    const void* __restrict__ tW2, const void* __restrict__ tb2,
    const void* __restrict__ tg2, const void* __restrict__ tbe2,
    const void* __restrict__ sW1w, const void* __restrict__ sb1,
    float* __restrict__ ddx, float* __restrict__ t2g,
    float* __restrict__ sW,
    float (&xb)[4][DIN][2], float (&t1b)[4][H1][2], float (&t2b)[4][DM][2])
{
    const int tid  = threadIdx.x;
    const int w    = tid >> 6;
    const int lane = tid & 63;
    const int r0   = blockIdx.x * 8 + w * 2;

    if (lane < 50) {
#pragma unroll
        for (int r = 0; r < 2; ++r) {
            const float2 xv = LD2<ISB>(text, (r0 + r) * 50 + lane);
            xb[w][2 * lane][r]     = xv.x;
            xb[w][2 * lane + 1][r] = xv.y;
        }
    }
    // ---- stage tW1 (100x128 = 6400 float2) ----
    for (int i = tid; i < 6400; i += 256)
        *(float2*)&sW[2 * i] = LD2<ISB>(tW1, i);
    __syncthreads();

    // ---- GEMM1 (100 -> 128) from LDS ----
    const float2 b1v = LD2<ISB>(tb1, lane);
    float ax0 = b1v.x, ay0 = b1v.y, ax1 = b1v.x, ay1 = b1v.y;
#pragma unroll 10
    for (int k = 0; k < DIN; ++k) {
        const float2 wv = *(const float2*)&sW[k * 128 + 2 * lane];
        const float2 xv = *(const float2*)&xb[w][k][0];
        ax0 += xv.x * wv.x; ay0 += xv.x * wv.y;
        ax1 += xv.y * wv.x; ay1 += xv.y * wv.y;
    }
    {   // LN(128)+LReLU
        float4 red = waveReduceSum4(make_float4(
            ax0 + ay0, ax0 * ax0 + ay0 * ay0,
            ax1 + ay1, ax1 * ax1 + ay1 * ay1));
        const float m0 = red.x * (1.f / 128.f);
        const float rs0 = rsqrtf(red.y * (1.f / 128.f) - m0 * m0 + 1e-5f);
        const float m1 = red.z * (1.f / 128.f);
        const float rs1 = rsqrtf(red.w * (1.f / 128.f) - m1 * m1 + 1e-5f);
        const float2 g = LD2<ISB>(tg1, lane), be = LD2<ISB>(tbe1, lane);
        float2 v;
        v.x = lrelu((ax0 - m0) * rs0 * g.x + be.x);
        v.y = lrelu((ax1 - m1) * rs1 * g.x + be.x);
        *(float2*)&t1b[w][2 * lane][0] = v;
        v.x = lrelu((ay0 - m0) * rs0 * g.y + be.y);
        v.y = lrelu((ay1 - m1) * rs1 * g.y + be.y);
        *(float2*)&t1b[w][2 * lane + 1][0] = v;
    }
    __syncthreads();                 // all waves done with tW1

    // ---- stage tW2 (128x100 = 6400 float2) ----
    for (int i = tid; i < 6400; i += 256)
        *(float2*)&sW[2 * i] = LD2<ISB>(tW2, i);
    __syncthreads();

    // ---- GEMM2 (128 -> 100) from LDS ----
    const bool act = lane < 50;
    const int  li  = act ? lane : 0;
    const float2 b2v = LD2<ISB>(tb2, li);
    float cx0 = b2v.x, cy0 = b2v.y, cx1 = b2v.x, cy1 = b2v.y;
#pragma unroll 8
    for (int k = 0; k < H1; ++k) {
        const float2 wv = *(const float2*)&sW[k * 100 + 2 * li];
        const float2 tv = *(const float2*)&t1b[w][k][0];
        cx0 += tv.x * wv.x; cy0 += tv.x * wv.y;
        cx1 += tv.y * wv.x; cy1 += tv.y * wv.y;
    }
    float u0x, u0y, u1x, u1y;
    {   // LN(100)+LReLU -> t2b, t2g
        float4 red = waveReduceSum4(act ? make_float4(
            cx0 + cy0, cx0 * cx0 + cy0 * cy0,
            cx1 + cy1, cx1 * cx1 + cy1 * cy1) : make_float4(0.f, 0.f, 0.f, 0.f));
        const float m0 = red.x * 0.01f;
        const float rs0 = rsqrtf(red.y * 0.01f - m0 * m0 + 1e-5f);
        const float m1 = red.z * 0.01f;
        const float rs1 = rsqrtf(red.w * 0.01f - m1 * m1 + 1e-5f);
        if (act) {
            const float2 g = LD2<ISB>(tg2, lane), be = LD2<ISB>(tbe2, lane);
            u0x = lrelu((cx0 - m0) * rs0 * g.x + be.x);
            u0y = lrelu((cy0 - m0) * rs0 * g.y + be.y);
            u1x = lrelu((cx1 - m1) * rs1 * g.x + be.x);
            u1y = lrelu((cy1 - m1) * rs1 * g.y + be.y);
            t2b[w][2 * lane][0] = u0x; t2b[w][2 * lane + 1][0] = u0y;
            t2b[w][2 * lane][1] = u1x; t2b[w][2 * lane + 1][1] = u1y;
            *(float2*)(t2g + (r0)     * DM + 2 * lane) = make_float2(u0x, u0y);
            *(float2*)(t2g + (r0 + 1) * DM + 2 * lane) = make_float2(u1x, u1y);
        }
    }
    __syncthreads();                 // all waves done with tW2

    // ---- stage sW1 (100x100 = 5000 float2) ----
    for (int i = tid; i < 5000; i += 256)
        *(float2*)&sW[2 * i] = LD2<ISB>(sW1w, i);
    __syncthreads();

    // ---- delta (100 cols) from LDS -> ddx {de, de*t2} ----
    const float2 sbv = LD2<ISB>(sb1, li);
    float dA0x = sbv.x, dA0y = sbv.y, dA1x = sbv.x, dA1y = sbv.y;
#pragma unroll 10
    for (int k = 0; k < DM; ++k) {
        const float2 wv = *(const float2*)&sW[k * 100 + 2 * li];
        const float2 tv = *(const float2*)&t2b[w][k][0];
        dA0x += tv.x * wv.x; dA0y += tv.x * wv.y;
        dA1x += tv.y * wv.x; dA1y += tv.y * wv.y;
    }
    if (act) {
        float de0 = softplusf(dA0x), de1 = softplusf(dA0y);
        float4 o;
        o.x = de0; o.y = de0 * u0x; o.z = de1; o.w = de1 * u0y;
        *(float4*)(ddx + (r0) * (2 * DM) + 4 * lane) = o;
        de0 = softplusf(dA1x); de1 = softplusf(dA1y);
        o.x = de0; o.y = de0 * u1x; o.z = de1; o.w = de1 * u1y;
        *(float4*)(ddx + (r0 + 1) * (2 * DM) + 4 * lane) = o;
    }
}

// prep duty: M33p row d3 (+ u,v cols; k0 on d3==0). Uses sW[0..943] as scratch.
template<bool ISB>
__device__ __forceinline__ void a_prep(
    const void* __restrict__ sW2, const void* __restrict__ sb2,
    const void* __restrict__ sW3, const void* __restrict__ sb3,
    float* __restrict__ M33p, float* __restrict__ k0w, float* __restrict__ sW,
    int d3)
{
    const int tid = threadIdx.x;
    const int w = tid >> 6, lane = tid & 63;
    float* W3row = sW;          // 300
    float* b2v   = sW + 320;    // 300
    float* b3v   = sW + 640;    // 300
    for (int i = tid; i < 300; i += 256) {
        W3row[i] = LD<ISB>(sW3, d3 * 300 + i);
        b2v[i]   = LD<ISB>(sb2, i);
        b3v[i]   = LD<ISB>(sb3, i);
    }
    __syncthreads();
    // wave w: d2 rows {w*25 .. w*25+24}, groups of 4 (6 groups + 1 leftover)
    for (int g = 0; g < 6; ++g) {
        const int d2 = w * 25 + g * 4;
        float4 p = make_float4(0.f, 0.f, 0.f, 0.f);
#pragma unroll
        for (int rep = 0; rep < 5; ++rep) {
            const int n = lane + 64 * rep;
            if (n < 300) {
                const float w3 = W3row[n];
                p.x += LD<ISB>(sW2, (d2 + 0) * 300 + n) * w3;
                p.y += LD<ISB>(sW2, (d2 + 1) * 300 + n) * w3;
                p.z += LD<ISB>(sW2, (d2 + 2) * 300 + n) * w3;
                p.w += LD<ISB>(sW2, (d2 + 3) * 300 + n) * w3;
            }
        }
        p = waveReduceSum4(p);
        if (lane == 0) {
            M33p[d3 * 102 + d2 + 0] = p.x;
            M33p[d3 * 102 + d2 + 1] = p.y;
            M33p[d3 * 102 + d2 + 2] = p.z;
            M33p[d3 * 102 + d2 + 3] = p.w;
        }
    }
    {   // leftover row d2 = w*25+24, plus u (w0), v (w1), k0 (w2, d3==0)
        const int d2 = w * 25 + 24;
        float4 p = make_float4(0.f, 0.f, 0.f, 0.f);
#pragma unroll
        for (int rep = 0; rep < 5; ++rep) {
            const int n = lane + 64 * rep;
            if (n < 300) {
                p.x += LD<ISB>(sW2, d2 * 300 + n) * W3row[n];
                if (w == 0) p.y += W3row[n] * b2v[n];                       // u[d3]
                if (w == 1) p.y += LD<ISB>(sW2, d3 * 300 + n) * b3v[n];     // v[d3]
                if (w == 2 && d3 == 0) p.y += b2v[n] * b3v[n];              // k0
            }
        }
        p = waveReduceSum4(p);
        if (lane == 0) {
            M33p[d3 * 102 + d2] = p.x;
            if (w == 0) M33p[d3 * 102 + 100] = p.y;
            if (w == 1) M33p[d3 * 102 + 101] = p.y;
            if (w == 2 && d3 == 0) k0w[0] = p.y;
        }
    }
}

template<bool ISB>
__device__ __forceinline__ void a_check(
    const void* __restrict__ sA, float* __restrict__ Afl,
    float* __restrict__ sW, int j)
{
    const int tid = threadIdx.x;
    const float a0 = LD<ISB>(sA, 0);
    bool ok = true;
    for (int i = j * 3750 + tid; i < (j + 1) * 3750; i += 256)
        ok &= (LD<ISB>(sA, i) == a0);
    if (tid == 0) sW[960] = 1.f;
    __syncthreads();
    if (!ok) sW[960] = 0.f;          // benign same-value race
    __syncthreads();
    if (tid == 0) Afl[j] = sW[960];
    if (j == 0 && tid == 1) Afl[8] = a0;
}

template<bool ISB>
__device__ __forceinline__ void a_mkv(
    const void* __restrict__ cW1, const void* __restrict__ cb1,
    const void* __restrict__ cW2, const void* __restrict__ cb2,
    float* __restrict__ Mkv)
{
    const int t = threadIdx.x;
    if (t < 200) {
        const int d = t >> 1, j = t & 1;
        float m = 0.f;
#pragma unroll 5
        for (int i = 0; i < 50; ++i)
            m += LD<ISB>(cW1, d * 50 + i) * LD<ISB>(cW2, 2 * i + j);
        Mkv[t] = m;
    } else if (t < 202) {
        const int j = t - 200;
        float kv = LD<ISB>(cb2, j);
#pragma unroll 5
        for (int i = 0; i < 50; ++i)
            kv += LD<ISB>(cb1, i) * LD<ISB>(cW2, 2 * i + j);
        Mkv[200 + j] = kv;
    }
}

__global__ __launch_bounds__(256) void k_A(
    const void* text,
    const void* tW1, const void* tb1, const void* tg1, const void* tbe1,
    const void* tW2, const void* tb2, const void* tg2, const void* tbe2,
    const void* sW1w, const void* sb1,
    const void* sW2, const void* sb2, const void* sW3, const void* sb3,
    const void* sA,
    const void* cW1, const void* cb1, const void* cW2, const void* cb2,
    float* ddx, float* t2g, float* Mkv, float* M33p, float* k0w, float* Afl,
    const unsigned short* probe)
{
    __shared__ __align__(16) float sW[12800];       // 51.2 KB (phase weights)
    __shared__ __align__(16) float xb[4][DIN][2];
    __shared__ __align__(16) float t1b[4][H1][2];
    __shared__ __align__(16) float t2b[4][DM][2];
    const bool isb = detect_bf16(probe);
    const int blk = blockIdx.x;
    if (blk < 504) {
        if (isb) a_main<true >(text, tW1, tb1, tg1, tbe1, tW2, tb2, tg2, tbe2,
                               sW1w, sb1, ddx, t2g, sW, xb, t1b, t2b);
        else     a_main<false>(text, tW1, tb1, tg1, tbe1, tW2, tb2, tg2, tbe2,
                               sW1w, sb1, ddx, t2g, sW, xb, t1b, t2b);
    } else if (blk < 604) {
        if (isb) a_prep<true >(sW2, sb2, sW3, sb3, M33p, k0w, sW, blk - 504);
        else     a_prep<false>(sW2, sb2, sW3, sb3, M33p, k0w, sW, blk - 504);
    } else if (blk < 612) {
        if (isb) a_check<true >(sA, Afl, sW, blk - 604);
        else     a_check<false>(sA, Afl, sW, blk - 604);
    } else {
        if (isb) a_mkv<true >(cW1, cb1, cW2, cb2, Mkv);
        else     a_mkv<false>(cW1, cb1, cW2, cb2, Mkv);
    }
}

// ---------------------------------------------------------------------------
// k_GYH (fast path): grid 512 = (batch, t-chunk of 8), XCD-grouped so all 8
// tc-blocks of a batch share blockIdx%8 (same XCD L2). Fuses G + Y + head.
//   G[t,s] = k0 + Z[t][100] + rv_s + sum_k Z[t][k]*T2[s][k]   (LDS only)
//   V[d][s] = num[s,d]/E[s,d],  E[t,d] = exp(a * prefix(de)),  streamed
//   y[t,d] = E[t,d] * sum_{s<=t} G[t,s] V[d,s];  out = y@Mkv + kv  (in-wave)
// sV aliases sT2 (dead after G phase): LDS 34.5KB -> 4 blocks/CU.
// ---------------------------------------------------------------------------
template<bool ISB>
__device__ __forceinline__ void gyh_impl(
    const float* __restrict__ t2g, const float* __restrict__ ddx,
    const float* __restrict__ M33p, const float* __restrict__ k0w,
    const float* __restrict__ Mkv, const float* __restrict__ Afl,
    void* __restrict__ outp,
    float* __restrict__ sBig, float (&sZ)[8][104],
    float* __restrict__ sv, float* __restrict__ srv,
    float (&sG)[8][64], float (&sE)[8][100])
{
    // XCD-aware decode: xcd = bid%8 gets batches {xcd*8 .. xcd*8+7} entirely.
    const int bid = blockIdx.x;
    const int xcd = bid & 7;
    const int j   = bid >> 3;            // 0..63
    const int b   = xcd * 8 + (j >> 3);
    const int tc  = j & 7;
    const int tid = threadIdx.x;
    const int w = tid >> 6, lane = tid & 63;

    float* __restrict__ sT2 = sBig;      // [64*102] phase 1-3
    float* __restrict__ sV  = sBig;      // [100*65] phase 4-5 (alias; sT2 dead)

    // ---- stage T2 (whole batch) ----
    for (int i = tid; i < 3150; i += 256) {
        const float2 v = *(const float2*)(t2g + b * 6300 + 2 * i);
        const int t = i / 50, k = 2 * (i % 50);
        sT2[t * 102 + k]     = v.x;
        sT2[t * 102 + k + 1] = v.y;
    }
    if (tid < 100) sv[tid] = M33p[tid * 102 + 101];
    __syncthreads();

    if (lane < 16) {                 // rv[s], 16 s per wave
        const int s = w * 16 + lane;
        if (s < SEQ) {
            float acc = 0.f;
#pragma unroll 4
            for (int k = 0; k < 100; ++k) acc += sT2[s * 102 + k] * sv[k];
            srv[s] = acc;
        }
    }

    {   // Z rows (2 per wave) via one ring-prefetched M33p stream
        const int l2 = (lane < 51) ? 2 * lane : 0;
        int tg2i[2];
#pragma unroll
        for (int r = 0; r < 2; ++r) {
            const int t = tc * 8 + w * 2 + r;
            tg2i[r] = (t < SEQ) ? t : SEQ - 1;
        }
        float2 acc[2];
        acc[0] = make_float2(0.f, 0.f);
        acc[1] = make_float2(0.f, 0.f);
        float2 ring[10];
#pragma unroll
        for (int j2 = 0; j2 < 10; ++j2) ring[j2] = *(const float2*)(M33p + j2 * 102 + l2);
        for (int kk = 0; kk < 100; kk += 10) {
#pragma unroll
            for (int j2 = 0; j2 < 10; ++j2) {
                const int jj = kk + j2;
                const float2 wv = ring[j2];
                if (jj + 10 < 100) ring[j2] = *(const float2*)(M33p + (jj + 10) * 102 + l2);
#pragma unroll
                for (int r = 0; r < 2; ++r) {
                    const float tv = sT2[tg2i[r] * 102 + jj];
                    acc[r].x += tv * wv.x;
                    acc[r].y += tv * wv.y;
                }
            }
        }
        if (lane < 51) {
#pragma unroll
            for (int r = 0; r < 2; ++r)
                *(float2*)&sZ[w * 2 + r][l2] = acc[r];
        }
    }
    __syncthreads();

    {   // ---- G rows (2 per wave), kept in LDS; tv shared across both rows
        const float kz = k0w[0];
        const int s = lane;
        const int sc = (s < SEQ) ? s : SEQ - 1;
        float acc0 = kz + sZ[w * 2][100]     + srv[sc];
        float acc1 = kz + sZ[w * 2 + 1][100] + srv[sc];
#pragma unroll 5
        for (int k2 = 0; k2 < 50; ++k2) {
            const float2 tv = *(const float2*)&sT2[sc * 102 + 2 * k2];
            const float2 z0 = *(const float2*)&sZ[w * 2][2 * k2];
            const float2 z1 = *(const float2*)&sZ[w * 2 + 1][2 * k2];
            acc0 += z0.x * tv.x + z0.y * tv.y;
            acc1 += z1.x * tv.x + z1.y * tv.y;
        }
        if (s < SEQ) {
            if (tc * 8 + w * 2     < SEQ) sG[w * 2][s]     = acc0;
            if (tc * 8 + w * 2 + 1 < SEQ) sG[w * 2 + 1][s] = acc1;
        }
    }
    __syncthreads();                 // last sT2 read done; sV may now overwrite

    {   // ---- V / E stream: thread d in [0,100), prefix over s ----
        const float a = Afl[8];
        const int tmax = (tc * 8 + 7 < SEQ) ? tc * 8 + 7 : SEQ - 1;
        if (tid < 100) {
            const int d = tid;
            float D = 0.f;
            for (int s = 0; s <= tmax; ++s) {
                const float2 dn = *(const float2*)(ddx + (b * SEQ + s) * 200 + 2 * d);
                D += dn.x;                       // de
                const float E = __expf(a * D);
                sV[d * 65 + s] = dn.y / E;       // num / E
                const int tl = s - tc * 8;
                if (tl >= 0) sE[tl][d] = E;
            }
        }
    }
    __syncthreads();

    {   // ---- Y + head (2 t-rows per wave; in-wave reduce over d) ----
        const int li = (lane < 50) ? lane : 49;
        const float4 mk = *(const float4*)(Mkv + 4 * li);   // M[2li][0..1], M[2li+1][0..1]
        float4 oacc = make_float4(0.f, 0.f, 0.f, 0.f);
#pragma unroll
        for (int r = 0; r < 2; ++r) {
            const int tl = w * 2 + r;
            const int t  = tc * 8 + tl;
            if (t >= SEQ) continue;
            float acc0 = 0.f, acc1 = 0.f;
            const float* v0 = sV + (2 * li) * 65;
            const float* v1 = sV + (2 * li + 1) * 65;
            for (int s = 0; s <= t; ++s) {
                const float g = sG[tl][s];
                acc0 += g * v0[s];
                acc1 += g * v1[s];
            }
            const float2 E = *(const float2*)&sE[tl][2 * li];
            const float y0 = (lane < 50) ? E.x * acc0 : 0.f;
            const float y1 = (lane < 50) ? E.y * acc1 : 0.f;
            if (r == 0) { oacc.x = y0 * mk.x + y1 * mk.z; oacc.y = y0 * mk.y + y1 * mk.w; }
            else        { oacc.z = y0 * mk.x + y1 * mk.z; oacc.w = y0 * mk.y + y1 * mk.w; }
        }
        oacc = waveReduceSum4(oacc);
        if (lane == 0) {
            const float kv0 = Mkv[200], kv1 = Mkv[201];
#pragma unroll
            for (int r = 0; r < 2; ++r) {
                const int t = tc * 8 + w * 2 + r;
                if (t >= SEQ) continue;
                const int row = b * SEQ + t;
                const float o0 = (r == 0 ? oacc.x : oacc.z) + kv0;
                const float o1 = (r == 0 ? oacc.y : oacc.w) + kv1;
                if (ISB) {
                    ((bf16*)outp)[row * 2 + 0] = __float2bfloat16(o0);
                    ((bf16*)outp)[row * 2 + 1] = __float2bfloat16(o1);
                } else {
                    *(float2*)((float*)outp + row * 2) = make_float2(o0, o1);
                }
            }
        }
    }
}

__global__ __launch_bounds__(256, 4) void k_GYH(
    const float* __restrict__ t2g, const float* __restrict__ ddx,
    const float* __restrict__ M33p, const float* __restrict__ k0w,
    const float* __restrict__ Mkv, const float* __restrict__ Afl,
    void* __restrict__ outp, const unsigned short* __restrict__ probe)
{
    __shared__ __align__(16) float sBig[64 * 102];  // sT2 (phase 1-3) / sV (4-5)
    __shared__ __align__(16) float sZ[8][104];
    __shared__ float sv[100];
    __shared__ float srv[64];
    __shared__ __align__(16) float sG[8][64];
    __shared__ __align__(16) float sE[8][100];
    if (!flags_uniform(Afl)) return;
    if (detect_bf16(probe))
        gyh_impl<true >(t2g, ddx, M33p, k0w, Mkv, Afl, outp, sBig, sZ, sv, srv, sG, sE);
    else
        gyh_impl<false>(t2g, ddx, M33p, k0w, Mkv, Afl, outp, sBig, sZ, sv, srv, sG, sE);
}

// ---------------------------------------------------------------------------
// Fallback kernels (gated off when A uniform): R9 k_B + k_scan (row-major y).
// ---------------------------------------------------------------------------
template<bool ISB>
__device__ __forceinline__ float4 LD4(const void* p, int i) {
    if (ISB) {
        const uint2 u = ((const uint2*)p)[i];
        float4 r;
        r.x = __uint_as_float(u.x << 16);
        r.y = __uint_as_float(u.x & 0xffff0000u);
        r.z = __uint_as_float(u.y << 16);
        r.w = __uint_as_float(u.y & 0xffff0000u);
        return r;
    } else return ((const float4*)p)[i];
}

template<bool ISB>
__device__ __forceinline__ void b_impl(
    const float* __restrict__ t2g,
    const void* __restrict__ sW2, const void* __restrict__ sb2,
    const void* __restrict__ sW3, const void* __restrict__ sb3,
    float* __restrict__ BC, float (&sT)[DM][8])
{
    const int t  = threadIdx.x;
    const int r0 = blockIdx.x * 8;
    if (t < DM) {
#pragma unroll
        for (int r = 0; r < 8; ++r) sT[t][r] = t2g[(r0 + r) * DM + t];
    }
    __syncthreads();
    const bool isB = t < 75;
    const bool valid = t < 150;
    const int colbase = isB ? 4 * t : (valid ? 4 * (t - 75) : 0);
    const void* Wp   = isB ? sW2 : sW3;
    const void* bias = isB ? sb2 : sb3;
    const int rs4 = NS >> 2;
    const int cb4 = colbase >> 2;
    float4 acc[8];
    {
        const float4 bv = LD4<ISB>(bias, cb4);
#pragma unroll
        for (int r = 0; r < 8; ++r) acc[r] = bv;
    }
    float4 ring[4];
#pragma unroll
    for (int j = 0; j < 4; ++j) ring[j] = LD4<ISB>(Wp, j * rs4 + cb4);
    for (int kk = 0; kk < DM; kk += 4) {
#pragma unroll
        for (int j = 0; j < 4; ++j) {
            const int k = kk + j;
            const float4 wv = ring[j];
            if (k + 4 < DM) ring[j] = LD4<ISB>(Wp, (k + 4) * rs4 + cb4);
            const float4 lo = *(const float4*)&sT[k][0];
            const float4 hi = *(const float4*)&sT[k][4];
            acc[0].x += lo.x * wv.x; acc[0].y += lo.x * wv.y; acc[0].z += lo.x * wv.z; acc[0].w += lo.x * wv.w;
            acc[1].x += lo.y * wv.x; acc[1].y += lo.y * wv.y; acc[1].z += lo.y * wv.z; acc[1].w += lo.y * wv.w;
            acc[2].x += lo.z * wv.x; acc[2].y += lo.z * wv.y; acc[2].z += lo.z * wv.z; acc[2].w += lo.z * wv.w;
            acc[3].x += lo.w * wv.x; acc[3].y += lo.w * wv.y; acc[3].z += lo.w * wv.z; acc[3].w += lo.w * wv.w;
            acc[4].x += hi.x * wv.x; acc[4].y += hi.x * wv.y; acc[4].z += hi.x * wv.z; acc[4].w += hi.x * wv.w;
            acc[5].x += hi.y * wv.x; acc[5].y += hi.y * wv.y; acc[5].z += hi.y * wv.z; acc[5].w += hi.y * wv.w;
            acc[6].x += hi.z * wv.x; acc[6].y += hi.z * wv.y; acc[6].z += hi.z * wv.z; acc[6].w += hi.z * wv.w;
            acc[7].x += hi.w * wv.x; acc[7].y += hi.w * wv.y; acc[7].z += hi.w * wv.z; acc[7].w += hi.w * wv.w;
        }
    }
    if (valid) {
        const int off = isB ? 0 : 1;
#pragma unroll
        for (int r = 0; r < 8; ++r) {
            float* bp = BC + (r0 + r) * (2 * NS) + 2 * colbase + off;
            bp[0] = acc[r].x; bp[2] = acc[r].y;
            bp[4] = acc[r].z; bp[6] = acc[r].w;
        }
    }
}

__global__ __launch_bounds__(192, 1) void k_B(
    const float* t2g, const void* sW2, const void* sb2,
    const void* sW3, const void* sb3, float* BC,
    const float* Afl, const unsigned short* probe)
{
    __shared__ __align__(16) float sT[DM][8];
    if (flags_uniform(Afl)) return;
    if (detect_bf16(probe)) b_impl<true >(t2g, sW2, sb2, sW3, sb3, BC, sT);
    else                    b_impl<false>(t2g, sW2, sb2, sW3, sb3, BC, sT);
}

template<bool ISB>
__device__ __forceinline__ void scan_impl(
    const float* __restrict__ ddx, const float* __restrict__ BC,
    const void* __restrict__ sA, float* __restrict__ y,
    float (&sacc)[4][16][2][68])
{
    const int w    = threadIdx.x >> 6;
    const int lane = threadIdx.x & 63;
    const int wid  = blockIdx.x * 4 + w;
    const int b    = wid / 50;
    const int dp   = wid % 50;
    const int d0   = 2 * dp, d1 = d0 + 1;

    int nc[5]; bool nv[5];
    float A0[5], A1[5], h0[5], h1[5];
#pragma unroll
    for (int c = 0; c < 5; ++c) {
        const int n = lane + 64 * c;
        nv[c] = n < NS;
        nc[c] = nv[c] ? n : 0;
        A0[c] = nv[c] ? LD<ISB>(sA, d0 * NS + nc[c]) : 0.f;
        A1[c] = nv[c] ? LD<ISB>(sA, d1 * NS + nc[c]) : 0.f;
        h0[c] = 0.f; h1[c] = 0.f;
    }
    const float* ddp = ddx + (b * SEQ) * (2 * DM) + 4 * dp;
    const float* BCp = BC  + (b * SEQ) * (2 * NS);
    float*       yp  = y   + (b * SEQ) * DM + d0;

    float4 pdd[3];
    float2 pbc[3][5];
#pragma unroll
    for (int j = 0; j < 3; ++j) {
        pdd[j] = *(const float4*)(ddp + j * (2 * DM));
#pragma unroll
        for (int c = 0; c < 5; ++c)
            pbc[j][c] = nv[c] ? *(const float2*)(BCp + j * (2 * NS) + 2 * nc[c])
                              : make_float2(0.f, 0.f);
    }
    const int pr = lane >> 1;
    const int hh = lane & 1;
    const int sa = pr & 15;
    const int aa = pr >> 4;

#pragma unroll 3
    for (int l = 0; l < SEQ; ++l) {
        const int bi = l % 3;
        const float4 dd = pdd[bi];
        float2 bc[5];
#pragma unroll
        for (int c = 0; c < 5; ++c) bc[c] = pbc[bi][c];
        if (l + 3 < SEQ) {
            pdd[bi] = *(const float4*)(ddp + (l + 3) * (2 * DM));
#pragma unroll
            for (int c = 0; c < 5; ++c)
                pbc[bi][c] = nv[c] ? *(const float2*)(BCp + (l + 3) * (2 * NS) + 2 * nc[c])
                                   : make_float2(0.f, 0.f);
        }
        float a0 = 0.f, a1 = 0.f;
#pragma unroll
        for (int c = 0; c < 5; ++c) {
            h0[c] = __expf(dd.x * A0[c]) * h0[c] + dd.y * bc[c].x;
            a0 += bc[c].y * h0[c];
            h1[c] = __expf(dd.z * A1[c]) * h1[c] + dd.w * bc[c].x;
            a1 += bc[c].y * h1[c];
        }
        const int s = l & 15;
        sacc[w][s][0][lane] = a0;
        sacc[w][s][1][lane] = a1;

        if (s == 15 || l == SEQ - 1) {
            const int l0 = l & ~15;
            const int cs = l - l0 + 1;
            float sum = 0.f;
            if (sa < cs) {
                const float* rowp = &sacc[w][sa][aa][hh * 32];
#pragma unroll
                for (int i = 0; i < 8; ++i) {
                    const float4 v = *(const float4*)(rowp + 4 * i);
                    sum += v.x + v.y + v.z + v.w;
                }
            }
            sum += __shfl_xor(sum, 1, 64);
            if (hh == 0 && sa < cs) yp[(l0 + sa) * DM + aa] = sum;
        }
    }
}

__global__ __launch_bounds__(256) void k_scan(
    const float* ddx, const float* BC, const void* sA, float* y,
    const float* Afl, const unsigned short* probe)
{
    __shared__ __align__(16) float sacc[4][16][2][68];
    if (flags_uniform(Afl)) return;
    if (detect_bf16(probe)) scan_impl<true >(ddx, BC, sA, y, sacc);
    else                    scan_impl<false>(ddx, BC, sA, y, sacc);
}

// ---------------------------------------------------------------------------
// k_headF: FALLBACK-only head. out[row] = y[row] @ M + k, row-major y.
// ---------------------------------------------------------------------------
template<bool ISB>
__device__ __forceinline__ void headf_impl(
    const float* __restrict__ y, const float* __restrict__ Mkv,
    void* __restrict__ outp)
{
    const int row = blockIdx.x * 256 + threadIdx.x;
    if (row >= ROWS) return;
    float a0 = Mkv[200], a1 = Mkv[201];
    const float* yr = y + row * DM;
#pragma unroll 4
    for (int k = 0; k < DM; ++k) {
        const float v = yr[k];
        const float2 m = *(const float2*)(Mkv + 2 * k);
        a0 += v * m.x;
        a1 += v * m.y;
    }
    if (ISB) {
        ((bf16*)outp)[row * 2 + 0] = __float2bfloat16(a0);
        ((bf16*)outp)[row * 2 + 1] = __float2bfloat16(a1);
    } else {
        *(float2*)((float*)outp + row * 2) = make_float2(a0, a1);
    }
}

__global__ __launch_bounds__(256) void k_headF(
    const float* y, const float* Mkv, void* outp,
    const float* Afl, const unsigned short* probe)
{
    if (flags_uniform(Afl)) return;
    if (detect_bf16(probe)) headf_impl<true >(y, Mkv, outp);
    else                    headf_impl<false>(y, Mkv, outp);
}

// ---------------------------------------------------------------------------
extern "C" void kernel_launch(void* const* d_in, const int* in_sizes, int n_in,
                              void* d_out, int out_size, void* d_ws, size_t ws_size,
                              hipStream_t stream)
{
    const void* text = d_in[0];
    const void* tW1  = d_in[3];
    const void* tb1  = d_in[4];
    const void* tg1  = d_in[5];
    const void* tbe1 = d_in[6];
    const void* tW2  = d_in[7];
    const void* tb2  = d_in[8];
    const void* tg2  = d_in[9];
    const void* tbe2 = d_in[10];
    const void* sW1  = d_in[11];
    const void* sb1  = d_in[12];
    const void* sW2  = d_in[13];
    const void* sb2  = d_in[14];
    const void* sW3  = d_in[15];
    const void* sb3  = d_in[16];
    const void* sA   = d_in[17];
    const void* cW1  = d_in[34];
    const void* cb1  = d_in[35];
    const void* cW2  = d_in[36];
    const void* cb2  = d_in[37];
    const unsigned short* probe = (const unsigned short*)d_in[3];

    float* ws   = (float*)d_ws;
    float* ddx  = ws;                         // ROWS*200
    float* BCv  = ddx + ROWS * 2 * DM;        // ROWS*600 (fallback BC)
    float* yv   = BCv + ROWS * 2 * NS;        // ROWS*100 (t2g; fallback y)
    float* Mkv  = yv + ROWS * DM;             // 202
    float* M33p = Mkv + 202;                  // 100*102
    float* k0w  = M33p + 10200;               // 1
    float* Afl  = k0w + 1;                    // 9 (8 flags + a)
    float* t2g  = yv;                         // alias: consumed before y write

    k_A<<<613, 256, 0, stream>>>(
        text, tW1, tb1, tg1, tbe1, tW2, tb2, tg2, tbe2,
        sW1, sb1, sW2, sb2, sW3, sb3, sA,
        cW1, cb1, cW2, cb2,
        ddx, t2g, Mkv, M33p, k0w, Afl, probe);

    // Fast path: one fused kernel, G/V/E/Y/head all in LDS, writes d_out.
    k_GYH<<<BATCH * 8, 256, 0, stream>>>(t2g, ddx, M33p, k0w, Mkv, Afl,
                                         d_out, probe);

    // Fallback path (gated off when A uniform):
    k_B<<<ROWS / 8, 192, 0, stream>>>(t2g, sW2, sb2, sW3, sb3, BCv, Afl, probe);
    k_scan<<<3200 / 4, 256, 0, stream>>>(ddx, BCv, sA, yv, Afl, probe);
    k_headF<<<(ROWS + 255) / 256, 256, 0, stream>>>(yv, Mkv, d_out, Afl, probe);
}

// Round 3
// 179.196 us; speedup vs baseline: 1.2473x; 1.0748x over previous
//
#include <hip/hip_runtime.h>
#include <hip/hip_bf16.h>

// Simple_6270652252303. Inputs float32 (detector-verified; bf16 path kept).
// sA constant (runtime-verified) => closed-form S6:
//   y[b,t,d] = E_t[d] * sum_{s<=t} G_b[t,s] * dx_s[d]/E_s[d]
//   G_b[t,s] = Z_t.T2_s + ru_t + rv_s + k0,  Z = T2@M33p (cols 100=u,101=v)
// R15: k_GYH restructured. R14 was 43us at VALUBusy 10% (~90% stall):
//   global-latency-exposed loops (M33p ring, 63-step serial ddx prefix) +
//   tc-tail imbalance + VGPR-64 squeeze. Now: grid 256 = (b, t-quartile of
//   16), 512 threads, ~78KB LDS, ALL inner loops LDS-only (M33p + ddx tile
//   staged), prefix redundancy 8x->4x and quartile-limited, no VGPR cap.
//   LDS reuse: M33p region -> V[s][d]+E (dead after Z/G); T2 region -> de.
// k_A (R12 structure) unchanged; k_B/k_scan/k_headF are gated fallbacks.

typedef __hip_bfloat16 bf16;

#define BATCH 64
#define SEQ   63
#define ROWS  (BATCH * SEQ)   // 4032
#define DIN   100
#define H1    128
#define DM    100
#define NS    300

__device__ __forceinline__ float2 up2(unsigned u) {
    float2 r;
    r.x = __uint_as_float(u << 16);
    r.y = __uint_as_float(u & 0xffff0000u);
    return r;
}
template<bool ISB>
__device__ __forceinline__ float LD(const void* p, int i) {
    if (ISB) return __bfloat162float(((const bf16*)p)[i]);
    else     return ((const float*)p)[i];
}
template<bool ISB>
__device__ __forceinline__ float2 LD2(const void* p, int i) {   // elems 2i,2i+1
    if (ISB) return up2(((const unsigned*)p)[i]);
    else     return ((const float2*)p)[i];
}
__device__ __forceinline__ float waveReduceSum(float v) {
#pragma unroll
    for (int off = 32; off > 0; off >>= 1) v += __shfl_xor(v, off, 64);
    return v;
}
__device__ __forceinline__ float4 waveReduceSum4(float4 v) {
#pragma unroll
    for (int off = 32; off > 0; off >>= 1) {
        const float a = __shfl_xor(v.x, off, 64);
        const float b = __shfl_xor(v.y, off, 64);
        const float c = __shfl_xor(v.z, off, 64);
        const float d = __shfl_xor(v.w, off, 64);
        v.x += a; v.y += b; v.z += c; v.w += d;
    }
    return v;
}
__device__ __forceinline__ float lrelu(float x) { return x >= 0.f ? x : 0.01f * x; }
__device__ __forceinline__ float softplusf(float x) {
    return (x > 20.f) ? x : log1pf(__expf(x));
}
__device__ __forceinline__ bool flags_uniform(const float* __restrict__ f) {
    bool u = true;
#pragma unroll
    for (int i = 0; i < 8; ++i) u &= (f[i] > 0.5f);
    return u;
}
__device__ __forceinline__ bool detect_bf16(const unsigned short* __restrict__ probe) {
    const int l = threadIdx.x & 63;
    const unsigned u0 = probe[l * 2];
    const unsigned u1 = probe[l * 2 + 1];
    const float v0 = fabsf(__uint_as_float(u0 << 16));
    const float v1 = fabsf(__uint_as_float(u1 << 16));
    const bool big = !(v0 < 1000.f) || !(v1 < 1000.f);
    const bool zero_even = (u0 == 0u);
    const unsigned long long mb = __ballot(big);
    const unsigned long long mz = __ballot(zero_even);
    return (mb == 0ULL) && (__popcll(mz) < 32);
}

// ---------------------------------------------------------------------------
// k_A: grid 613. Blocks 0..503: main row pipeline (8 rows/block, 2 rows/wave).
//   Weights staged in LDS per phase (tW1 -> tW2 -> sW1), block barriers
//   between phases; inner loops are pure VALU + ds_read (no global latency).
// Blocks 504..603: M33p row (d3 = blk-504) + u/v cols (+k0 on 504).
// Blocks 604..611: A-uniformity check. Block 612: collapsed head Mkv.
// ---------------------------------------------------------------------------
template<bool ISB>
__device__ __forceinline__ void a_main(
    const void* __restrict__ text,
    const void* __restrict__ tW1, const void* __restrict__ tb1,
    const void* __restrict__ tg1, const void* __restrict__ tbe1,
    const void* __restrict__ tW2, const void* __restrict__ tb2,
    const void* __restrict__ tg2, const void* __restrict__ tbe2,
    const void* __restrict__ sW1w, const void* __restrict__ sb1,
    float* __restrict__ ddx, float* __restrict__ t2g,
    float* __restrict__ sW,
    float (&xb)[4][DIN][2], float (&t1b)[4][H1][2], float (&t2b)[4][DM][2])
{
    const int tid  = threadIdx.x;
    const int w    = tid >> 6;
    const int lane = tid & 63;
    const int r0   = blockIdx.x * 8 + w * 2;

    if (lane < 50) {
#pragma unroll
        for (int r = 0; r < 2; ++r) {
            const float2 xv = LD2<ISB>(text, (r0 + r) * 50 + lane);
            xb[w][2 * lane][r]     = xv.x;
            xb[w][2 * lane + 1][r] = xv.y;
        }
    }
    // ---- stage tW1 (100x128 = 6400 float2) ----
    for (int i = tid; i < 6400; i += 256)
        *(float2*)&sW[2 * i] = LD2<ISB>(tW1, i);
    __syncthreads();

    // ---- GEMM1 (100 -> 128) from LDS ----
    const float2 b1v = LD2<ISB>(tb1, lane);
    float ax0 = b1v.x, ay0 = b1v.y, ax1 = b1v.x, ay1 = b1v.y;
#pragma unroll 10
    for (int k = 0; k < DIN; ++k) {
        const float2 wv = *(const float2*)&sW[k * 128 + 2 * lane];
        const float2 xv = *(const float2*)&xb[w][k][0];
        ax0 += xv.x * wv.x; ay0 += xv.x * wv.y;
        ax1 += xv.y * wv.x; ay1 += xv.y * wv.y;
    }
    {   // LN(128)+LReLU
        float4 red = waveReduceSum4(make_float4(
            ax0 + ay0, ax0 * ax0 + ay0 * ay0,
            ax1 + ay1, ax1 * ax1 + ay1 * ay1));
        const float m0 = red.x * (1.f / 128.f);
        const float rs0 = rsqrtf(red.y * (1.f / 128.f) - m0 * m0 + 1e-5f);
        const float m1 = red.z * (1.f / 128.f);
        const float rs1 = rsqrtf(red.w * (1.f / 128.f) - m1 * m1 + 1e-5f);
        const float2 g = LD2<ISB>(tg1, lane), be = LD2<ISB>(tbe1, lane);
        float2 v;
        v.x = lrelu((ax0 - m0) * rs0 * g.x + be.x);
        v.y = lrelu((ax1 - m1) * rs1 * g.x + be.x);
        *(float2*)&t1b[w][2 * lane][0] = v;
        v.x = lrelu((ay0 - m0) * rs0 * g.y + be.y);
        v.y = lrelu((ay1 - m1) * rs1 * g.y + be.y);
        *(float2*)&t1b[w][2 * lane + 1][0] = v;
    }
    __syncthreads();                 // all waves done with tW1

    // ---- stage tW2 (128x100 = 6400 float2) ----
    for (int i = tid; i < 6400; i += 256)
        *(float2*)&sW[2 * i] = LD2<ISB>(tW2, i);
    __syncthreads();

    // ---- GEMM2 (128 -> 100) from LDS ----
    const bool act = lane < 50;
    const int  li  = act ? lane : 0;
    const float2 b2v = LD2<ISB>(tb2, li);
    float cx0 = b2v.x, cy0 = b2v.y, cx1 = b2v.x, cy1 = b2v.y;
#pragma unroll 8
    for (int k = 0; k < H1; ++k) {
        const float2 wv = *(const float2*)&sW[k * 100 + 2 * li];
        const float2 tv = *(const float2*)&t1b[w][k][0];
        cx0 += tv.x * wv.x; cy0 += tv.x * wv.y;
        cx1 += tv.y * wv.x; cy1 += tv.y * wv.y;
    }
    float u0x, u0y, u1x, u1y;
    {   // LN(100)+LReLU -> t2b, t2g
        float4 red = waveReduceSum4(act ? make_float4(
            cx0 + cy0, cx0 * cx0 + cy0 * cy0,
            cx1 + cy1, cx1 * cx1 + cy1 * cy1) : make_float4(0.f, 0.f, 0.f, 0.f));
        const float m0 = red.x * 0.01f;
        const float rs0 = rsqrtf(red.y * 0.01f - m0 * m0 + 1e-5f);
        const float m1 = red.z * 0.01f;
        const float rs1 = rsqrtf(red.w * 0.01f - m1 * m1 + 1e-5f);
        if (act) {
            const float2 g = LD2<ISB>(tg2, lane), be = LD2<ISB>(tbe2, lane);
            u0x = lrelu((cx0 - m0) * rs0 * g.x + be.x);
            u0y = lrelu((cy0 - m0) * rs0 * g.y + be.y);
            u1x = lrelu((cx1 - m1) * rs1 * g.x + be.x);
            u1y = lrelu((cy1 - m1) * rs1 * g.y + be.y);
            t2b[w][2 * lane][0] = u0x; t2b[w][2 * lane + 1][0] = u0y;
            t2b[w][2 * lane][1] = u1x; t2b[w][2 * lane + 1][1] = u1y;
            *(float2*)(t2g + (r0)     * DM + 2 * lane) = make_float2(u0x, u0y);
            *(float2*)(t2g + (r0 + 1) * DM + 2 * lane) = make_float2(u1x, u1y);
        }
    }
    __syncthreads();                 // all waves done with tW2

    // ---- stage sW1 (100x100 = 5000 float2) ----
    for (int i = tid; i < 5000; i += 256)
        *(float2*)&sW[2 * i] = LD2<ISB>(sW1w, i);
    __syncthreads();

    // ---- delta (100 cols) from LDS -> ddx {de, de*t2} ----
    const float2 sbv = LD2<ISB>(sb1, li);
    float dA0x = sbv.x, dA0y = sbv.y, dA1x = sbv.x, dA1y = sbv.y;
#pragma unroll 10
    for (int k = 0; k < DM; ++k) {
        const float2 wv = *(const float2*)&sW[k * 100 + 2 * li];
        const float2 tv = *(const float2*)&t2b[w][k][0];
        dA0x += tv.x * wv.x; dA0y += tv.x * wv.y;
        dA1x += tv.y * wv.x; dA1y += tv.y * wv.y;
    }
    if (act) {
        float de0 = softplusf(dA0x), de1 = softplusf(dA0y);
        float4 o;
        o.x = de0; o.y = de0 * u0x; o.z = de1; o.w = de1 * u0y;
        *(float4*)(ddx + (r0) * (2 * DM) + 4 * lane) = o;
        de0 = softplusf(dA1x); de1 = softplusf(dA1y);
        o.x = de0; o.y = de0 * u1x; o.z = de1; o.w = de1 * u1y;
        *(float4*)(ddx + (r0 + 1) * (2 * DM) + 4 * lane) = o;
    }
}

// prep duty: M33p row d3 (+ u,v cols; k0 on d3==0). Uses sW[0..943] as scratch.
template<bool ISB>
__device__ __forceinline__ void a_prep(
    const void* __restrict__ sW2, const void* __restrict__ sb2,
    const void* __restrict__ sW3, const void* __restrict__ sb3,
    float* __restrict__ M33p, float* __restrict__ k0w, float* __restrict__ sW,
    int d3)
{
    const int tid = threadIdx.x;
    const int w = tid >> 6, lane = tid & 63;
    float* W3row = sW;          // 300
    float* b2v   = sW + 320;    // 300
    float* b3v   = sW + 640;    // 300
    for (int i = tid; i < 300; i += 256) {
        W3row[i] = LD<ISB>(sW3, d3 * 300 + i);
        b2v[i]   = LD<ISB>(sb2, i);
        b3v[i]   = LD<ISB>(sb3, i);
    }
    __syncthreads();
    // wave w: d2 rows {w*25 .. w*25+24}, groups of 4 (6 groups + 1 leftover)
    for (int g = 0; g < 6; ++g) {
        const int d2 = w * 25 + g * 4;
        float4 p = make_float4(0.f, 0.f, 0.f, 0.f);
#pragma unroll
        for (int rep = 0; rep < 5; ++rep) {
            const int n = lane + 64 * rep;
            if (n < 300) {
                const float w3 = W3row[n];
                p.x += LD<ISB>(sW2, (d2 + 0) * 300 + n) * w3;
                p.y += LD<ISB>(sW2, (d2 + 1) * 300 + n) * w3;
                p.z += LD<ISB>(sW2, (d2 + 2) * 300 + n) * w3;
                p.w += LD<ISB>(sW2, (d2 + 3) * 300 + n) * w3;
            }
        }
        p = waveReduceSum4(p);
        if (lane == 0) {
            M33p[d3 * 102 + d2 + 0] = p.x;
            M33p[d3 * 102 + d2 + 1] = p.y;
            M33p[d3 * 102 + d2 + 2] = p.z;
            M33p[d3 * 102 + d2 + 3] = p.w;
        }
    }
    {   // leftover row d2 = w*25+24, plus u (w0), v (w1), k0 (w2, d3==0)
        const int d2 = w * 25 + 24;
        float4 p = make_float4(0.f, 0.f, 0.f, 0.f);
#pragma unroll
        for (int rep = 0; rep < 5; ++rep) {
            const int n = lane + 64 * rep;
            if (n < 300) {
                p.x += LD<ISB>(sW2, d2 * 300 + n) * W3row[n];
                if (w == 0) p.y += W3row[n] * b2v[n];                       // u[d3]
                if (w == 1) p.y += LD<ISB>(sW2, d3 * 300 + n) * b3v[n];     // v[d3]
                if (w == 2 && d3 == 0) p.y += b2v[n] * b3v[n];              // k0
            }
        }
        p = waveReduceSum4(p);
        if (lane == 0) {
            M33p[d3 * 102 + d2] = p.x;
            if (w == 0) M33p[d3 * 102 + 100] = p.y;
            if (w == 1) M33p[d3 * 102 + 101] = p.y;
            if (w == 2 && d3 == 0) k0w[0] = p.y;
        }
    }
}

template<bool ISB>
__device__ __forceinline__ void a_check(
    const void* __restrict__ sA, float* __restrict__ Afl,
    float* __restrict__ sW, int j)
{
    const int tid = threadIdx.x;
    const float a0 = LD<ISB>(sA, 0);
    bool ok = true;
    for (int i = j * 3750 + tid; i < (j + 1) * 3750; i += 256)
        ok &= (LD<ISB>(sA, i) == a0);
    if (tid == 0) sW[960] = 1.f;
    __syncthreads();
    if (!ok) sW[960] = 0.f;          // benign same-value race
    __syncthreads();
    if (tid == 0) Afl[j] = sW[960];
    if (j == 0 && tid == 1) Afl[8] = a0;
}

template<bool ISB>
__device__ __forceinline__ void a_mkv(
    const void* __restrict__ cW1, const void* __restrict__ cb1,
    const void* __restrict__ cW2, const void* __restrict__ cb2,
    float* __restrict__ Mkv)
{
    const int t = threadIdx.x;
    if (t < 200) {
        const int d = t >> 1, j = t & 1;
        float m = 0.f;
#pragma unroll 5
        for (int i = 0; i < 50; ++i)
            m += LD<ISB>(cW1, d * 50 + i) * LD<ISB>(cW2, 2 * i + j);
        Mkv[t] = m;
    } else if (t < 202) {
        const int j = t - 200;
        float kv = LD<ISB>(cb2, j);
#pragma unroll 5
        for (int i = 0; i < 50; ++i)
            kv += LD<ISB>(cb1, i) * LD<ISB>(cW2, 2 * i + j);
        Mkv[200 + j] = kv;
    }
}

__global__ __launch_bounds__(256) void k_A(
    const void* text,
    const void* tW1, const void* tb1, const void* tg1, const void* tbe1,
    const void* tW2, const void* tb2, const void* tg2, const void* tbe2,
    const void* sW1w, const void* sb1,
    const void* sW2, const void* sb2, const void* sW3, const void* sb3,
    const void* sA,
    const void* cW1, const void* cb1, const void* cW2, const void* cb2,
    float* ddx, float* t2g, float* Mkv, float* M33p, float* k0w, float* Afl,
    const unsigned short* probe)
{
    __shared__ __align__(16) float sW[12800];       // 51.2 KB (phase weights)
    __shared__ __align__(16) float xb[4][DIN][2];
    __shared__ __align__(16) float t1b[4][H1][2];
    __shared__ __align__(16) float t2b[4][DM][2];
    const bool isb = detect_bf16(probe);
    const int blk = blockIdx.x;
    if (blk < 504) {
        if (isb) a_main<true >(text, tW1, tb1, tg1, tbe1, tW2, tb2, tg2, tbe2,
                               sW1w, sb1, ddx, t2g, sW, xb, t1b, t2b);
        else     a_main<false>(text, tW1, tb1, tg1, tbe1, tW2, tb2, tg2, tbe2,
                               sW1w, sb1, ddx, t2g, sW, xb, t1b, t2b);
    } else if (blk < 604) {
        if (isb) a_prep<true >(sW2, sb2, sW3, sb3, M33p, k0w, sW, blk - 504);
        else     a_prep<false>(sW2, sb2, sW3, sb3, M33p, k0w, sW, blk - 504);
    } else if (blk < 612) {
        if (isb) a_check<true >(sA, Afl, sW, blk - 604);
        else     a_check<false>(sA, Afl, sW, blk - 604);
    } else {
        if (isb) a_mkv<true >(cW1, cb1, cW2, cb2, Mkv);
        else     a_mkv<false>(cW1, cb1, cW2, cb2, Mkv);
    }
}

// ---------------------------------------------------------------------------
// k_GYH (fast path, R15): grid 256 = (b, quartile q of 16 t-rows), 512 thr.
// All-LDS inner loops. Phases:
//  P1 stage T2[<=63][102], M33p[100][102], Mkv          (global->LDS, coalesced)
//  P2 srv[s] (8 s/wave, wave-reduce) + Z own rows (2/wave, k-loop from LDS)
//  P3 G[zr][s] = k0 + Z[t][100] + srv[s] + sum_k Z[t][k] T2[s][k]
//  P4 stage ddx tile -> de (T2 region), num (M33p region)   [both dead]
//  P5 prefix (100 thr): V[s][d] = num*exp(-aD) in-place, E own rows
//  P6 Y+head: 2 t-rows/wave, in-wave reduce, write d_out
// LDS ~78KB -> 1 block/CU, 8 waves. XCD-grouped: batch's 4 blocks same XCD.
// ---------------------------------------------------------------------------
template<bool ISB>
__device__ __forceinline__ void gyh_impl(
    const float* __restrict__ t2g, const float* __restrict__ ddx,
    const float* __restrict__ M33p, const float* __restrict__ k0w,
    const float* __restrict__ Mkv, const float* __restrict__ Afl,
    void* __restrict__ outp,
    float* __restrict__ sT2, float* __restrict__ sM,
    float* __restrict__ sZ, float* __restrict__ sG,
    float* __restrict__ srv, float* __restrict__ sMk)
{
    // XCD-aware decode: xcd = bid%8 gets batches {xcd*8 .. xcd*8+7}.
    const int bid = blockIdx.x;
    const int xcd = bid & 7;
    const int jj  = bid >> 3;            // 0..31
    const int b   = xcd * 8 + (jj >> 2);
    const int q   = jj & 3;              // t-quartile
    const int tid = threadIdx.x;
    const int w = tid >> 6, lane = tid & 63;

    const int tmax  = (q * 16 + 15 < SEQ) ? q * 16 + 15 : SEQ - 1; // 15/31/47/62
    const int srows = tmax + 1;

    // ---- P1: stage T2 rows [0..tmax], M33p, Mkv ----
    for (int i = tid; i < srows * 50; i += 512) {
        const float2 v = ((const float2*)t2g)[b * 3150 + i];
        const int t = i / 50, k2 = i % 50;
        sT2[t * 102 + 2 * k2]     = v.x;
        sT2[t * 102 + 2 * k2 + 1] = v.y;
    }
    for (int i = tid; i < 5100; i += 512)
        *(float2*)&sM[2 * i] = ((const float2*)M33p)[i];
    if (tid < 202) sMk[tid] = Mkv[tid];
    __syncthreads();

    // ---- P2: srv (8 s per wave) + Z own rows (2 per wave) ----
    {
        const float mv0 = sM[lane * 102 + 101];
        const float mv1 = (lane < 36) ? sM[(64 + lane) * 102 + 101] : 0.f;
#pragma unroll
        for (int g = 0; g < 2; ++g) {
            float4 p;
            float acc[4];
#pragma unroll
            for (int i = 0; i < 4; ++i) {
                const int s = w * 8 + g * 4 + i;
                const int scl = (s <= tmax) ? s : 0;
                float a = sT2[scl * 102 + lane] * mv0;
                if (lane < 36) a += sT2[scl * 102 + 64 + lane] * mv1;
                acc[i] = a;
            }
            p = waveReduceSum4(make_float4(acc[0], acc[1], acc[2], acc[3]));
            if (lane == 0) {
                const int s0 = w * 8 + g * 4;
                srv[s0 + 0] = p.x; srv[s0 + 1] = p.y;
                srv[s0 + 2] = p.z; srv[s0 + 3] = p.w;
            }
        }
    }
    {
        const int l2 = (lane < 51) ? 2 * lane : 0;
        const int zr0 = w * 2, zr1 = w * 2 + 1;
        const int t0 = q * 16 + zr0;         // always <= tmax
        const int t1 = q * 16 + zr1;         // q3,w7: 63 -> invalid
        const int tc1 = (t1 <= tmax) ? t1 : tmax;
        float2 a0 = make_float2(0.f, 0.f);
        float2 a1 = make_float2(0.f, 0.f);
#pragma unroll 4
        for (int k = 0; k < 100; ++k) {
            const float2 wv = *(const float2*)&sM[k * 102 + l2];
            const float x0 = sT2[t0 * 102 + k];
            const float x1 = sT2[tc1 * 102 + k];
            a0.x += x0 * wv.x; a0.y += x0 * wv.y;
            a1.x += x1 * wv.x; a1.y += x1 * wv.y;
        }
        if (lane < 51) {
            *(float2*)&sZ[zr0 * 102 + l2] = a0;
            if (t1 <= tmax) *(float2*)&sZ[zr1 * 102 + l2] = a1;
        }
    }
    __syncthreads();

    // ---- P3: G own rows (2 per wave, lane = s) ----
    {
        const float kz = k0w[0];
        const int sc  = (lane <= tmax) ? lane : tmax;
        const int zr0 = w * 2, zr1 = w * 2 + 1;
        const int t1  = q * 16 + zr1;
        float g0 = kz + sZ[zr0 * 102 + 100] + srv[sc];
        float g1 = kz + sZ[zr1 * 102 + 100] + srv[sc];
#pragma unroll 5
        for (int k2 = 0; k2 < 50; ++k2) {
            const float2 tv = *(const float2*)&sT2[sc * 102 + 2 * k2];
            const float2 z0 = *(const float2*)&sZ[zr0 * 102 + 2 * k2];
            const float2 z1 = *(const float2*)&sZ[zr1 * 102 + 2 * k2];
            g0 += z0.x * tv.x + z0.y * tv.y;
            g1 += z1.x * tv.x + z1.y * tv.y;
        }
        if (lane <= tmax) {
            sG[zr0 * 64 + lane] = g0;
            if (t1 <= tmax) sG[zr1 * 64 + lane] = g1;
        }
    }
    __syncthreads();

    // ---- P4: stage ddx tile -> de (sT2 region), num (sM region) ----
    for (int i = tid; i < srows * 100; i += 512) {
        const float2 v = ((const float2*)ddx)[b * 6300 + i];
        sT2[i] = v.x;                 // de
        sM[i]  = v.y;                 // num (becomes V in-place)
    }
    __syncthreads();

    // ---- P5: prefix over s (100 threads, LDS-only) ----
    {
        const float av = Afl[8];
        if (tid < 100) {
            const int d = tid;
            float D = 0.f;
            for (int s = 0; s <= tmax; ++s) {
                D += sT2[s * 100 + d];
                const float En = __expf(-av * D);
                sM[s * 100 + d] = sM[s * 100 + d] * En;      // V[s][d]
                const int zr = s - q * 16;
                if (zr >= 0) sM[6400 + zr * 100 + d] = __expf(av * D); // E
            }
        }
    }
    __syncthreads();

    // ---- P6: Y + head (2 t-rows per wave; in-wave reduce over d) ----
    {
        const int li = (lane < 50) ? lane : 49;
        const float4 mk = *(const float4*)&sMk[4 * li];
        float4 oc = make_float4(0.f, 0.f, 0.f, 0.f);
#pragma unroll
        for (int r = 0; r < 2; ++r) {
            const int zr = w * 2 + r;
            const int t  = q * 16 + zr;
            float o0 = 0.f, o1 = 0.f;
            if (t < SEQ) {
                float a0 = 0.f, a1 = 0.f;
                const int nf = (t + 1) >> 1;
                const float* gp = &sG[zr * 64];
                for (int s2 = 0; s2 < nf; ++s2) {
                    const float2 g2 = *(const float2*)&gp[2 * s2];
                    const float2 v0 = *(const float2*)&sM[(2 * s2) * 100 + 2 * li];
                    const float2 v1 = *(const float2*)&sM[(2 * s2 + 1) * 100 + 2 * li];
                    a0 += g2.x * v0.x + g2.y * v1.x;
                    a1 += g2.x * v0.y + g2.y * v1.y;
                }
                if ((t & 1) == 0) {        // even t: tail s = t
                    const float gg = gp[t];
                    const float2 vt = *(const float2*)&sM[t * 100 + 2 * li];
                    a0 += gg * vt.x; a1 += gg * vt.y;
                }
                const float2 e2 = *(const float2*)&sM[6400 + zr * 100 + 2 * li];
                const float y0 = (lane < 50) ? e2.x * a0 : 0.f;
                const float y1 = (lane < 50) ? e2.y * a1 : 0.f;
                o0 = y0 * mk.x + y1 * mk.z;
                o1 = y0 * mk.y + y1 * mk.w;
            }
            if (r == 0) { oc.x = o0; oc.y = o1; }
            else        { oc.z = o0; oc.w = o1; }
        }
        oc = waveReduceSum4(oc);
        if (lane == 0) {
            const float kv0 = sMk[200], kv1 = sMk[201];
#pragma unroll
            for (int r = 0; r < 2; ++r) {
                const int t = q * 16 + w * 2 + r;
                if (t >= SEQ) continue;
                const int row = b * SEQ + t;
                const float o0 = (r == 0 ? oc.x : oc.z) + kv0;
                const float o1 = (r == 0 ? oc.y : oc.w) + kv1;
                if (ISB) {
                    ((bf16*)outp)[row * 2 + 0] = __float2bfloat16(o0);
                    ((bf16*)outp)[row * 2 + 1] = __float2bfloat16(o1);
                } else {
                    *(float2*)((float*)outp + row * 2) = make_float2(o0, o1);
                }
            }
        }
    }
}

__global__ __launch_bounds__(512) void k_GYH(
    const float* __restrict__ t2g, const float* __restrict__ ddx,
    const float* __restrict__ M33p, const float* __restrict__ k0w,
    const float* __restrict__ Mkv, const float* __restrict__ Afl,
    void* __restrict__ outp, const unsigned short* __restrict__ probe)
{
    __shared__ __align__(16) float sT2[6426];    // T2[63][102]; then de[6300]
    __shared__ __align__(16) float sM[10240];    // M33p[100][102]; then V[63][100]@0 + E[16][100]@6400
    __shared__ __align__(16) float sZ[1632];     // Z own [16][102]
    __shared__ __align__(16) float sG[1024];     // G own [16][64]
    __shared__ __align__(16) float srv[64];
    __shared__ __align__(16) float sMk[204];
    if (!flags_uniform(Afl)) return;
    if (detect_bf16(probe))
        gyh_impl<true >(t2g, ddx, M33p, k0w, Mkv, Afl, outp, sT2, sM, sZ, sG, srv, sMk);
    else
        gyh_impl<false>(t2g, ddx, M33p, k0w, Mkv, Afl, outp, sT2, sM, sZ, sG, srv, sMk);
}

// ---------------------------------------------------------------------------
// Fallback kernels (gated off when A uniform): R9 k_B + k_scan (row-major y).
// ---------------------------------------------------------------------------
template<bool ISB>
__device__ __forceinline__ float4 LD4(const void* p, int i) {
    if (ISB) {
        const uint2 u = ((const uint2*)p)[i];
        float4 r;
        r.x = __uint_as_float(u.x << 16);
        r.y = __uint_as_float(u.x & 0xffff0000u);
        r.z = __uint_as_float(u.y << 16);
        r.w = __uint_as_float(u.y & 0xffff0000u);
        return r;
    } else return ((const float4*)p)[i];
}

template<bool ISB>
__device__ __forceinline__ void b_impl(
    const float* __restrict__ t2g,
    const void* __restrict__ sW2, const void* __restrict__ sb2,
    const void* __restrict__ sW3, const void* __restrict__ sb3,
    float* __restrict__ BC, float (&sT)[DM][8])
{
    const int t  = threadIdx.x;
    const int r0 = blockIdx.x * 8;
    if (t < DM) {
#pragma unroll
        for (int r = 0; r < 8; ++r) sT[t][r] = t2g[(r0 + r) * DM + t];
    }
    __syncthreads();
    const bool isB = t < 75;
    const bool valid = t < 150;
    const int colbase = isB ? 4 * t : (valid ? 4 * (t - 75) : 0);
    const void* Wp   = isB ? sW2 : sW3;
    const void* bias = isB ? sb2 : sb3;
    const int rs4 = NS >> 2;
    const int cb4 = colbase >> 2;
    float4 acc[8];
    {
        const float4 bv = LD4<ISB>(bias, cb4);
#pragma unroll
        for (int r = 0; r < 8; ++r) acc[r] = bv;
    }
    float4 ring[4];
#pragma unroll
    for (int j = 0; j < 4; ++j) ring[j] = LD4<ISB>(Wp, j * rs4 + cb4);
    for (int kk = 0; kk < DM; kk += 4) {
#pragma unroll
        for (int j = 0; j < 4; ++j) {
            const int k = kk + j;
            const float4 wv = ring[j];
            if (k + 4 < DM) ring[j] = LD4<ISB>(Wp, (k + 4) * rs4 + cb4);
            const float4 lo = *(const float4*)&sT[k][0];
            const float4 hi = *(const float4*)&sT[k][4];
            acc[0].x += lo.x * wv.x; acc[0].y += lo.x * wv.y; acc[0].z += lo.x * wv.z; acc[0].w += lo.x * wv.w;
            acc[1].x += lo.y * wv.x; acc[1].y += lo.y * wv.y; acc[1].z += lo.y * wv.z; acc[1].w += lo.y * wv.w;
            acc[2].x += lo.z * wv.x; acc[2].y += lo.z * wv.y; acc[2].z += lo.z * wv.z; acc[2].w += lo.z * wv.w;
            acc[3].x += lo.w * wv.x; acc[3].y += lo.w * wv.y; acc[3].z += lo.w * wv.z; acc[3].w += lo.w * wv.w;
            acc[4].x += hi.x * wv.x; acc[4].y += hi.x * wv.y; acc[4].z += hi.x * wv.z; acc[4].w += hi.x * wv.w;
            acc[5].x += hi.y * wv.x; acc[5].y += hi.y * wv.y; acc[5].z += hi.y * wv.z; acc[5].w += hi.y * wv.w;
            acc[6].x += hi.z * wv.x; acc[6].y += hi.z * wv.y; acc[6].z += hi.z * wv.z; acc[6].w += hi.z * wv.w;
            acc[7].x += hi.w * wv.x; acc[7].y += hi.w * wv.y; acc[7].z += hi.w * wv.z; acc[7].w += hi.w * wv.w;
        }
    }
    if (valid) {
        const int off = isB ? 0 : 1;
#pragma unroll
        for (int r = 0; r < 8; ++r) {
            float* bp = BC + (r0 + r) * (2 * NS) + 2 * colbase + off;
            bp[0] = acc[r].x; bp[2] = acc[r].y;
            bp[4] = acc[r].z; bp[6] = acc[r].w;
        }
    }
}

__global__ __launch_bounds__(192, 1) void k_B(
    const float* t2g, const void* sW2, const void* sb2,
    const void* sW3, const void* sb3, float* BC,
    const float* Afl, const unsigned short* probe)
{
    __shared__ __align__(16) float sT[DM][8];
    if (flags_uniform(Afl)) return;
    if (detect_bf16(probe)) b_impl<true >(t2g, sW2, sb2, sW3, sb3, BC, sT);
    else                    b_impl<false>(t2g, sW2, sb2, sW3, sb3, BC, sT);
}

template<bool ISB>
__device__ __forceinline__ void scan_impl(
    const float* __restrict__ ddx, const float* __restrict__ BC,
    const void* __restrict__ sA, float* __restrict__ y,
    float (&sacc)[4][16][2][68])
{
    const int w    = threadIdx.x >> 6;
    const int lane = threadIdx.x & 63;
    const int wid  = blockIdx.x * 4 + w;
    const int b    = wid / 50;
    const int dp   = wid % 50;
    const int d0   = 2 * dp, d1 = d0 + 1;

    int nc[5]; bool nv[5];
    float A0[5], A1[5], h0[5], h1[5];
#pragma unroll
    for (int c = 0; c < 5; ++c) {
        const int n = lane + 64 * c;
        nv[c] = n < NS;
        nc[c] = nv[c] ? n : 0;
        A0[c] = nv[c] ? LD<ISB>(sA, d0 * NS + nc[c]) : 0.f;
        A1[c] = nv[c] ? LD<ISB>(sA, d1 * NS + nc[c]) : 0.f;
        h0[c] = 0.f; h1[c] = 0.f;
    }
    const float* ddp = ddx + (b * SEQ) * (2 * DM) + 4 * dp;
    const float* BCp = BC  + (b * SEQ) * (2 * NS);
    float*       yp  = y   + (b * SEQ) * DM + d0;

    float4 pdd[3];
    float2 pbc[3][5];
#pragma unroll
    for (int j = 0; j < 3; ++j) {
        pdd[j] = *(const float4*)(ddp + j * (2 * DM));
#pragma unroll
        for (int c = 0; c < 5; ++c)
            pbc[j][c] = nv[c] ? *(const float2*)(BCp + j * (2 * NS) + 2 * nc[c])
                              : make_float2(0.f, 0.f);
    }
    const int pr = lane >> 1;
    const int hh = lane & 1;
    const int sa = pr & 15;
    const int aa = pr >> 4;

#pragma unroll 3
    for (int l = 0; l < SEQ; ++l) {
        const int bi = l % 3;
        const float4 dd = pdd[bi];
        float2 bc[5];
#pragma unroll
        for (int c = 0; c < 5; ++c) bc[c] = pbc[bi][c];
        if (l + 3 < SEQ) {
            pdd[bi] = *(const float4*)(ddp + (l + 3) * (2 * DM));
#pragma unroll
            for (int c = 0; c < 5; ++c)
                pbc[bi][c] = nv[c] ? *(const float2*)(BCp + (l + 3) * (2 * NS) + 2 * nc[c])
                                   : make_float2(0.f, 0.f);
        }
        float a0 = 0.f, a1 = 0.f;
#pragma unroll
        for (int c = 0; c < 5; ++c) {
            h0[c] = __expf(dd.x * A0[c]) * h0[c] + dd.y * bc[c].x;
            a0 += bc[c].y * h0[c];
            h1[c] = __expf(dd.z * A1[c]) * h1[c] + dd.w * bc[c].x;
            a1 += bc[c].y * h1[c];
        }
        const int s = l & 15;
        sacc[w][s][0][lane] = a0;
        sacc[w][s][1][lane] = a1;

        if (s == 15 || l == SEQ - 1) {
            const int l0 = l & ~15;
            const int cs = l - l0 + 1;
            float sum = 0.f;
            if (sa < cs) {
                const float* rowp = &sacc[w][sa][aa][hh * 32];
#pragma unroll
                for (int i = 0; i < 8; ++i) {
                    const float4 v = *(const float4*)(rowp + 4 * i);
                    sum += v.x + v.y + v.z + v.w;
                }
            }
            sum += __shfl_xor(sum, 1, 64);
            if (hh == 0 && sa < cs) yp[(l0 + sa) * DM + aa] = sum;
        }
    }
}

__global__ __launch_bounds__(256) void k_scan(
    const float* ddx, const float* BC, const void* sA, float* y,
    const float* Afl, const unsigned short* probe)
{
    __shared__ __align__(16) float sacc[4][16][2][68];
    if (flags_uniform(Afl)) return;
    if (detect_bf16(probe)) scan_impl<true >(ddx, BC, sA, y, sacc);
    else                    scan_impl<false>(ddx, BC, sA, y, sacc);
}

// ---------------------------------------------------------------------------
// k_headF: FALLBACK-only head. out[row] = y[row] @ M + k, row-major y.
// ---------------------------------------------------------------------------
template<bool ISB>
__device__ __forceinline__ void headf_impl(
    const float* __restrict__ y, const float* __restrict__ Mkv,
    void* __restrict__ outp)
{
    const int row = blockIdx.x * 256 + threadIdx.x;
    if (row >= ROWS) return;
    float a0 = Mkv[200], a1 = Mkv[201];
    const float* yr = y + row * DM;
#pragma unroll 4
    for (int k = 0; k < DM; ++k) {
        const float v = yr[k];
        const float2 m = *(const float2*)(Mkv + 2 * k);
        a0 += v * m.x;
        a1 += v * m.y;
    }
    if (ISB) {
        ((bf16*)outp)[row * 2 + 0] = __float2bfloat16(a0);
        ((bf16*)outp)[row * 2 + 1] = __float2bfloat16(a1);
    } else {
        *(float2*)((float*)outp + row * 2) = make_float2(a0, a1);
    }
}

__global__ __launch_bounds__(256) void k_headF(
    const float* y, const float* Mkv, void* outp,
    const float* Afl, const unsigned short* probe)
{
    if (flags_uniform(Afl)) return;
    if (detect_bf16(probe)) headf_impl<true >(y, Mkv, outp);
    else                    headf_impl<false>(y, Mkv, outp);
}

// ---------------------------------------------------------------------------
extern "C" void kernel_launch(void* const* d_in, const int* in_sizes, int n_in,
                              void* d_out, int out_size, void* d_ws, size_t ws_size,
                              hipStream_t stream)
{
    const void* text = d_in[0];
    const void* tW1  = d_in[3];
    const void* tb1  = d_in[4];
    const void* tg1  = d_in[5];
    const void* tbe1 = d_in[6];
    const void* tW2  = d_in[7];
    const void* tb2  = d_in[8];
    const void* tg2  = d_in[9];
    const void* tbe2 = d_in[10];
    const void* sW1  = d_in[11];
    const void* sb1  = d_in[12];
    const void* sW2  = d_in[13];
    const void* sb2  = d_in[14];
    const void* sW3  = d_in[15];
    const void* sb3  = d_in[16];
    const void* sA   = d_in[17];
    const void* cW1  = d_in[34];
    const void* cb1  = d_in[35];
    const void* cW2  = d_in[36];
    const void* cb2  = d_in[37];
    const unsigned short* probe = (const unsigned short*)d_in[3];

    float* ws   = (float*)d_ws;
    float* ddx  = ws;                         // ROWS*200
    float* BCv  = ddx + ROWS * 2 * DM;        // ROWS*600 (fallback BC)
    float* yv   = BCv + ROWS * 2 * NS;        // ROWS*100 (t2g; fallback y)
    float* Mkv  = yv + ROWS * DM;             // 202
    float* M33p = Mkv + 202;                  // 100*102
    float* k0w  = M33p + 10200;               // 1
    float* Afl  = k0w + 1;                    // 9 (8 flags + a)
    float* t2g  = yv;                         // alias: consumed before y write

    k_A<<<613, 256, 0, stream>>>(
        text, tW1, tb1, tg1, tbe1, tW2, tb2, tg2, tbe2,
        sW1, sb1, sW2, sb2, sW3, sb3, sA,
        cW1, cb1, cW2, cb2,
        ddx, t2g, Mkv, M33p, k0w, Afl, probe);

    // Fast path: fused G/V/E/Y/head, all-LDS inner loops, writes d_out.
    k_GYH<<<BATCH * 4, 512, 0, stream>>>(t2g, ddx, M33p, k0w, Mkv, Afl,
                                         d_out, probe);

    // Fallback path (gated off when A uniform):
    k_B<<<ROWS / 8, 192, 0, stream>>>(t2g, sW2, sb2, sW3, sb3, BCv, Afl, probe);
    k_scan<<<3200 / 4, 256, 0, stream>>>(ddx, BCv, sA, yv, Afl, probe);
    k_headF<<<(ROWS + 255) / 256, 256, 0, stream>>>(yv, Mkv, d_out, Afl, probe);
}

// Round 4
// 175.141 us; speedup vs baseline: 1.2762x; 1.0232x over previous
//
#include <hip/hip_runtime.h>
#include <hip/hip_bf16.h>

// Simple_6270652252303. Inputs float32 (detector-verified; bf16 path kept).
// sA constant (runtime-verified) => closed-form S6:
//   y[b,t,d] = E_t[d] * sum_{s<=t} G_b[t,s] * dx_s[d]/E_s[d]
//   G_b[t,s] = Z_t.T2_s + ru_t + rv_s + k0,  Z = T2@M33p (cols 100=u,101=v)
// R16: k_GYH latency fixes (R15 was ~30us, phase-latency bound at 1 blk/CU):
//   (a) T14 async-STAGE: ddx tile loaded to a static 13xfloat2 reg array at
//       kernel entry; written to LDS only after P3 -> the 50KB staging
//       latency hides under P1-stage + Z + G compute (was serially exposed).
//   (b) P5 prefix 4-way chunked: chunk totals (400 thr) -> carry -> local
//       prefix+exp. Wall 63 dependent steps -> ~2x16; q3 tail shortened.
// k_A (R12 structure) unchanged; k_B/k_scan/k_headF are gated fallbacks.

typedef __hip_bfloat16 bf16;

#define BATCH 64
#define SEQ   63
#define ROWS  (BATCH * SEQ)   // 4032
#define DIN   100
#define H1    128
#define DM    100
#define NS    300

__device__ __forceinline__ float2 up2(unsigned u) {
    float2 r;
    r.x = __uint_as_float(u << 16);
    r.y = __uint_as_float(u & 0xffff0000u);
    return r;
}
template<bool ISB>
__device__ __forceinline__ float LD(const void* p, int i) {
    if (ISB) return __bfloat162float(((const bf16*)p)[i]);
    else     return ((const float*)p)[i];
}
template<bool ISB>
__device__ __forceinline__ float2 LD2(const void* p, int i) {   // elems 2i,2i+1
    if (ISB) return up2(((const unsigned*)p)[i]);
    else     return ((const float2*)p)[i];
}
__device__ __forceinline__ float waveReduceSum(float v) {
#pragma unroll
    for (int off = 32; off > 0; off >>= 1) v += __shfl_xor(v, off, 64);
    return v;
}
__device__ __forceinline__ float4 waveReduceSum4(float4 v) {
#pragma unroll
    for (int off = 32; off > 0; off >>= 1) {
        const float a = __shfl_xor(v.x, off, 64);
        const float b = __shfl_xor(v.y, off, 64);
        const float c = __shfl_xor(v.z, off, 64);
        const float d = __shfl_xor(v.w, off, 64);
        v.x += a; v.y += b; v.z += c; v.w += d;
    }
    return v;
}
__device__ __forceinline__ float lrelu(float x) { return x >= 0.f ? x : 0.01f * x; }
__device__ __forceinline__ float softplusf(float x) {
    return (x > 20.f) ? x : log1pf(__expf(x));
}
__device__ __forceinline__ bool flags_uniform(const float* __restrict__ f) {
    bool u = true;
#pragma unroll
    for (int i = 0; i < 8; ++i) u &= (f[i] > 0.5f);
    return u;
}
__device__ __forceinline__ bool detect_bf16(const unsigned short* __restrict__ probe) {
    const int l = threadIdx.x & 63;
    const unsigned u0 = probe[l * 2];
    const unsigned u1 = probe[l * 2 + 1];
    const float v0 = fabsf(__uint_as_float(u0 << 16));
    const float v1 = fabsf(__uint_as_float(u1 << 16));
    const bool big = !(v0 < 1000.f) || !(v1 < 1000.f);
    const bool zero_even = (u0 == 0u);
    const unsigned long long mb = __ballot(big);
    const unsigned long long mz = __ballot(zero_even);
    return (mb == 0ULL) && (__popcll(mz) < 32);
}

// ---------------------------------------------------------------------------
// k_A: grid 613. Blocks 0..503: main row pipeline (8 rows/block, 2 rows/wave).
//   Weights staged in LDS per phase (tW1 -> tW2 -> sW1), block barriers
//   between phases; inner loops are pure VALU + ds_read (no global latency).
// Blocks 504..603: M33p row (d3 = blk-504) + u/v cols (+k0 on 504).
// Blocks 604..611: A-uniformity check. Block 612: collapsed head Mkv.
// ---------------------------------------------------------------------------
template<bool ISB>
__device__ __forceinline__ void a_main(
    const void* __restrict__ text,
    const void* __restrict__ tW1, const void* __restrict__ tb1,
    const void* __restrict__ tg1, const void* __restrict__ tbe1,
    const void* __restrict__ tW2, const void* __restrict__ tb2,
    const void* __restrict__ tg2, const void* __restrict__ tbe2,
    const void* __restrict__ sW1w, const void* __restrict__ sb1,
    float* __restrict__ ddx, float* __restrict__ t2g,
    float* __restrict__ sW,
    float (&xb)[4][DIN][2], float (&t1b)[4][H1][2], float (&t2b)[4][DM][2])
{
    const int tid  = threadIdx.x;
    const int w    = tid >> 6;
    const int lane = tid & 63;
    const int r0   = blockIdx.x * 8 + w * 2;

    if (lane < 50) {
#pragma unroll
        for (int r = 0; r < 2; ++r) {
            const float2 xv = LD2<ISB>(text, (r0 + r) * 50 + lane);
            xb[w][2 * lane][r]     = xv.x;
            xb[w][2 * lane + 1][r] = xv.y;
        }
    }
    // ---- stage tW1 (100x128 = 6400 float2) ----
    for (int i = tid; i < 6400; i += 256)
        *(float2*)&sW[2 * i] = LD2<ISB>(tW1, i);
    __syncthreads();

    // ---- GEMM1 (100 -> 128) from LDS ----
    const float2 b1v = LD2<ISB>(tb1, lane);
    float ax0 = b1v.x, ay0 = b1v.y, ax1 = b1v.x, ay1 = b1v.y;
#pragma unroll 10
    for (int k = 0; k < DIN; ++k) {
        const float2 wv = *(const float2*)&sW[k * 128 + 2 * lane];
        const float2 xv = *(const float2*)&xb[w][k][0];
        ax0 += xv.x * wv.x; ay0 += xv.x * wv.y;
        ax1 += xv.y * wv.x; ay1 += xv.y * wv.y;
    }
    {   // LN(128)+LReLU
        float4 red = waveReduceSum4(make_float4(
            ax0 + ay0, ax0 * ax0 + ay0 * ay0,
            ax1 + ay1, ax1 * ax1 + ay1 * ay1));
        const float m0 = red.x * (1.f / 128.f);
        const float rs0 = rsqrtf(red.y * (1.f / 128.f) - m0 * m0 + 1e-5f);
        const float m1 = red.z * (1.f / 128.f);
        const float rs1 = rsqrtf(red.w * (1.f / 128.f) - m1 * m1 + 1e-5f);
        const float2 g = LD2<ISB>(tg1, lane), be = LD2<ISB>(tbe1, lane);
        float2 v;
        v.x = lrelu((ax0 - m0) * rs0 * g.x + be.x);
        v.y = lrelu((ax1 - m1) * rs1 * g.x + be.x);
        *(float2*)&t1b[w][2 * lane][0] = v;
        v.x = lrelu((ay0 - m0) * rs0 * g.y + be.y);
        v.y = lrelu((ay1 - m1) * rs1 * g.y + be.y);
        *(float2*)&t1b[w][2 * lane + 1][0] = v;
    }
    __syncthreads();                 // all waves done with tW1

    // ---- stage tW2 (128x100 = 6400 float2) ----
    for (int i = tid; i < 6400; i += 256)
        *(float2*)&sW[2 * i] = LD2<ISB>(tW2, i);
    __syncthreads();

    // ---- GEMM2 (128 -> 100) from LDS ----
    const bool act = lane < 50;
    const int  li  = act ? lane : 0;
    const float2 b2v = LD2<ISB>(tb2, li);
    float cx0 = b2v.x, cy0 = b2v.y, cx1 = b2v.x, cy1 = b2v.y;
#pragma unroll 8
    for (int k = 0; k < H1; ++k) {
        const float2 wv = *(const float2*)&sW[k * 100 + 2 * li];
        const float2 tv = *(const float2*)&t1b[w][k][0];
        cx0 += tv.x * wv.x; cy0 += tv.x * wv.y;
        cx1 += tv.y * wv.x; cy1 += tv.y * wv.y;
    }
    float u0x, u0y, u1x, u1y;
    {   // LN(100)+LReLU -> t2b, t2g
        float4 red = waveReduceSum4(act ? make_float4(
            cx0 + cy0, cx0 * cx0 + cy0 * cy0,
            cx1 + cy1, cx1 * cx1 + cy1 * cy1) : make_float4(0.f, 0.f, 0.f, 0.f));
        const float m0 = red.x * 0.01f;
        const float rs0 = rsqrtf(red.y * 0.01f - m0 * m0 + 1e-5f);
        const float m1 = red.z * 0.01f;
        const float rs1 = rsqrtf(red.w * 0.01f - m1 * m1 + 1e-5f);
        if (act) {
            const float2 g = LD2<ISB>(tg2, lane), be = LD2<ISB>(tbe2, lane);
            u0x = lrelu((cx0 - m0) * rs0 * g.x + be.x);
            u0y = lrelu((cy0 - m0) * rs0 * g.y + be.y);
            u1x = lrelu((cx1 - m1) * rs1 * g.x + be.x);
            u1y = lrelu((cy1 - m1) * rs1 * g.y + be.y);
            t2b[w][2 * lane][0] = u0x; t2b[w][2 * lane + 1][0] = u0y;
            t2b[w][2 * lane][1] = u1x; t2b[w][2 * lane + 1][1] = u1y;
            *(float2*)(t2g + (r0)     * DM + 2 * lane) = make_float2(u0x, u0y);
            *(float2*)(t2g + (r0 + 1) * DM + 2 * lane) = make_float2(u1x, u1y);
        }
    }
    __syncthreads();                 // all waves done with tW2

    // ---- stage sW1 (100x100 = 5000 float2) ----
    for (int i = tid; i < 5000; i += 256)
        *(float2*)&sW[2 * i] = LD2<ISB>(sW1w, i);
    __syncthreads();

    // ---- delta (100 cols) from LDS -> ddx {de, de*t2} ----
    const float2 sbv = LD2<ISB>(sb1, li);
    float dA0x = sbv.x, dA0y = sbv.y, dA1x = sbv.x, dA1y = sbv.y;
#pragma unroll 10
    for (int k = 0; k < DM; ++k) {
        const float2 wv = *(const float2*)&sW[k * 100 + 2 * li];
        const float2 tv = *(const float2*)&t2b[w][k][0];
        dA0x += tv.x * wv.x; dA0y += tv.x * wv.y;
        dA1x += tv.y * wv.x; dA1y += tv.y * wv.y;
    }
    if (act) {
        float de0 = softplusf(dA0x), de1 = softplusf(dA0y);
        float4 o;
        o.x = de0; o.y = de0 * u0x; o.z = de1; o.w = de1 * u0y;
        *(float4*)(ddx + (r0) * (2 * DM) + 4 * lane) = o;
        de0 = softplusf(dA1x); de1 = softplusf(dA1y);
        o.x = de0; o.y = de0 * u1x; o.z = de1; o.w = de1 * u1y;
        *(float4*)(ddx + (r0 + 1) * (2 * DM) + 4 * lane) = o;
    }
}

// prep duty: M33p row d3 (+ u,v cols; k0 on d3==0). Uses sW[0..943] as scratch.
template<bool ISB>
__device__ __forceinline__ void a_prep(
    const void* __restrict__ sW2, const void* __restrict__ sb2,
    const void* __restrict__ sW3, const void* __restrict__ sb3,
    float* __restrict__ M33p, float* __restrict__ k0w, float* __restrict__ sW,
    int d3)
{
    const int tid = threadIdx.x;
    const int w = tid >> 6, lane = tid & 63;
    float* W3row = sW;          // 300
    float* b2v   = sW + 320;    // 300
    float* b3v   = sW + 640;    // 300
    for (int i = tid; i < 300; i += 256) {
        W3row[i] = LD<ISB>(sW3, d3 * 300 + i);
        b2v[i]   = LD<ISB>(sb2, i);
        b3v[i]   = LD<ISB>(sb3, i);
    }
    __syncthreads();
    // wave w: d2 rows {w*25 .. w*25+24}, groups of 4 (6 groups + 1 leftover)
    for (int g = 0; g < 6; ++g) {
        const int d2 = w * 25 + g * 4;
        float4 p = make_float4(0.f, 0.f, 0.f, 0.f);
#pragma unroll
        for (int rep = 0; rep < 5; ++rep) {
            const int n = lane + 64 * rep;
            if (n < 300) {
                const float w3 = W3row[n];
                p.x += LD<ISB>(sW2, (d2 + 0) * 300 + n) * w3;
                p.y += LD<ISB>(sW2, (d2 + 1) * 300 + n) * w3;
                p.z += LD<ISB>(sW2, (d2 + 2) * 300 + n) * w3;
                p.w += LD<ISB>(sW2, (d2 + 3) * 300 + n) * w3;
            }
        }
        p = waveReduceSum4(p);
        if (lane == 0) {
            M33p[d3 * 102 + d2 + 0] = p.x;
            M33p[d3 * 102 + d2 + 1] = p.y;
            M33p[d3 * 102 + d2 + 2] = p.z;
            M33p[d3 * 102 + d2 + 3] = p.w;
        }
    }
    {   // leftover row d2 = w*25+24, plus u (w0), v (w1), k0 (w2, d3==0)
        const int d2 = w * 25 + 24;
        float4 p = make_float4(0.f, 0.f, 0.f, 0.f);
#pragma unroll
        for (int rep = 0; rep < 5; ++rep) {
            const int n = lane + 64 * rep;
            if (n < 300) {
                p.x += LD<ISB>(sW2, d2 * 300 + n) * W3row[n];
                if (w == 0) p.y += W3row[n] * b2v[n];                       // u[d3]
                if (w == 1) p.y += LD<ISB>(sW2, d3 * 300 + n) * b3v[n];     // v[d3]
                if (w == 2 && d3 == 0) p.y += b2v[n] * b3v[n];              // k0
            }
        }
        p = waveReduceSum4(p);
        if (lane == 0) {
            M33p[d3 * 102 + d2] = p.x;
            if (w == 0) M33p[d3 * 102 + 100] = p.y;
            if (w == 1) M33p[d3 * 102 + 101] = p.y;
            if (w == 2 && d3 == 0) k0w[0] = p.y;
        }
    }
}

template<bool ISB>
__device__ __forceinline__ void a_check(
    const void* __restrict__ sA, float* __restrict__ Afl,
    float* __restrict__ sW, int j)
{
    const int tid = threadIdx.x;
    const float a0 = LD<ISB>(sA, 0);
    bool ok = true;
    for (int i = j * 3750 + tid; i < (j + 1) * 3750; i += 256)
        ok &= (LD<ISB>(sA, i) == a0);
    if (tid == 0) sW[960] = 1.f;
    __syncthreads();
    if (!ok) sW[960] = 0.f;          // benign same-value race
    __syncthreads();
    if (tid == 0) Afl[j] = sW[960];
    if (j == 0 && tid == 1) Afl[8] = a0;
}

template<bool ISB>
__device__ __forceinline__ void a_mkv(
    const void* __restrict__ cW1, const void* __restrict__ cb1,
    const void* __restrict__ cW2, const void* __restrict__ cb2,
    float* __restrict__ Mkv)
{
    const int t = threadIdx.x;
    if (t < 200) {
        const int d = t >> 1, j = t & 1;
        float m = 0.f;
#pragma unroll 5
        for (int i = 0; i < 50; ++i)
            m += LD<ISB>(cW1, d * 50 + i) * LD<ISB>(cW2, 2 * i + j);
        Mkv[t] = m;
    } else if (t < 202) {
        const int j = t - 200;
        float kv = LD<ISB>(cb2, j);
#pragma unroll 5
        for (int i = 0; i < 50; ++i)
            kv += LD<ISB>(cb1, i) * LD<ISB>(cW2, 2 * i + j);
        Mkv[200 + j] = kv;
    }
}

__global__ __launch_bounds__(256) void k_A(
    const void* text,
    const void* tW1, const void* tb1, const void* tg1, const void* tbe1,
    const void* tW2, const void* tb2, const void* tg2, const void* tbe2,
    const void* sW1w, const void* sb1,
    const void* sW2, const void* sb2, const void* sW3, const void* sb3,
    const void* sA,
    const void* cW1, const void* cb1, const void* cW2, const void* cb2,
    float* ddx, float* t2g, float* Mkv, float* M33p, float* k0w, float* Afl,
    const unsigned short* probe)
{
    __shared__ __align__(16) float sW[12800];       // 51.2 KB (phase weights)
    __shared__ __align__(16) float xb[4][DIN][2];
    __shared__ __align__(16) float t1b[4][H1][2];
    __shared__ __align__(16) float t2b[4][DM][2];
    const bool isb = detect_bf16(probe);
    const int blk = blockIdx.x;
    if (blk < 504) {
        if (isb) a_main<true >(text, tW1, tb1, tg1, tbe1, tW2, tb2, tg2, tbe2,
                               sW1w, sb1, ddx, t2g, sW, xb, t1b, t2b);
        else     a_main<false>(text, tW1, tb1, tg1, tbe1, tW2, tb2, tg2, tbe2,
                               sW1w, sb1, ddx, t2g, sW, xb, t1b, t2b);
    } else if (blk < 604) {
        if (isb) a_prep<true >(sW2, sb2, sW3, sb3, M33p, k0w, sW, blk - 504);
        else     a_prep<false>(sW2, sb2, sW3, sb3, M33p, k0w, sW, blk - 504);
    } else if (blk < 612) {
        if (isb) a_check<true >(sA, Afl, sW, blk - 604);
        else     a_check<false>(sA, Afl, sW, blk - 604);
    } else {
        if (isb) a_mkv<true >(cW1, cb1, cW2, cb2, Mkv);
        else     a_mkv<false>(cW1, cb1, cW2, cb2, Mkv);
    }
}

// ---------------------------------------------------------------------------
// k_GYH (fast path, R16): grid 256 = (b, quartile q of 16 t-rows), 512 thr.
// All-LDS inner loops. Phases:
//  P0 issue ddx tile loads -> 13xfloat2 regs (T14: latency hides under P1-P3)
//  P1 stage T2[<=63][102], M33p[100][102], Mkv          (global->LDS)
//  P2 srv[s] (8 s/wave, wave-reduce) + Z own rows (2/wave, k-loop from LDS)
//  P3 G[zr][s] = k0 + Z[t][100] + srv[s] + sum_k Z[t][k] T2[s][k]
//  P4 regs -> de (T2 region), num (M33p region)         [pure LDS writes]
//  P5 prefix, 4-way chunked: totals (400thr) -> carry -> local prefix+exp
//  P6 Y+head: 2 t-rows/wave, in-wave reduce, write d_out
// LDS ~78KB -> 1 block/CU, 8 waves. XCD-grouped: batch's 4 blocks same XCD.
// ---------------------------------------------------------------------------
template<bool ISB>
__device__ __forceinline__ void gyh_impl(
    const float* __restrict__ t2g, const float* __restrict__ ddx,
    const float* __restrict__ M33p, const float* __restrict__ k0w,
    const float* __restrict__ Mkv, const float* __restrict__ Afl,
    void* __restrict__ outp,
    float* __restrict__ sT2, float* __restrict__ sM,
    float* __restrict__ sZ, float* __restrict__ sG,
    float* __restrict__ srv, float* __restrict__ sMk)
{
    // XCD-aware decode: xcd = bid%8 gets batches {xcd*8 .. xcd*8+7}.
    const int bid = blockIdx.x;
    const int xcd = bid & 7;
    const int jj  = bid >> 3;            // 0..31
    const int b   = xcd * 8 + (jj >> 2);
    const int q   = jj & 3;              // t-quartile
    const int tid = threadIdx.x;
    const int w = tid >> 6, lane = tid & 63;

    const int tmax  = (q * 16 + 15 < SEQ) ? q * 16 + 15 : SEQ - 1; // 15/31/47/62
    const int srows = tmax + 1;

    // ---- P0: issue ddx tile loads into regs (static indexing, rule #20) ----
    float2 rdd[13];
#pragma unroll
    for (int j = 0; j < 13; ++j) {
        const int i = tid + j * 512;
        rdd[j] = (i < srows * 100) ? ((const float2*)ddx)[b * 6300 + i]
                                   : make_float2(0.f, 0.f);
    }

    // ---- P1: stage T2 rows [0..tmax], M33p, Mkv ----
    for (int i = tid; i < srows * 50; i += 512) {
        const float2 v = ((const float2*)t2g)[b * 3150 + i];
        const int t = i / 50, k2 = i % 50;
        sT2[t * 102 + 2 * k2]     = v.x;
        sT2[t * 102 + 2 * k2 + 1] = v.y;
    }
    for (int i = tid; i < 5100; i += 512)
        *(float2*)&sM[2 * i] = ((const float2*)M33p)[i];
    if (tid < 202) sMk[tid] = Mkv[tid];
    __syncthreads();

    // ---- P2: srv (8 s per wave) + Z own rows (2 per wave) ----
    {
        const float mv0 = sM[lane * 102 + 101];
        const float mv1 = (lane < 36) ? sM[(64 + lane) * 102 + 101] : 0.f;
#pragma unroll
        for (int g = 0; g < 2; ++g) {
            float4 p;
            float acc[4];
#pragma unroll
            for (int i = 0; i < 4; ++i) {
                const int s = w * 8 + g * 4 + i;
                const int scl = (s <= tmax) ? s : 0;
                float a = sT2[scl * 102 + lane] * mv0;
                if (lane < 36) a += sT2[scl * 102 + 64 + lane] * mv1;
                acc[i] = a;
            }
            p = waveReduceSum4(make_float4(acc[0], acc[1], acc[2], acc[3]));
            if (lane == 0) {
                const int s0 = w * 8 + g * 4;
                srv[s0 + 0] = p.x; srv[s0 + 1] = p.y;
                srv[s0 + 2] = p.z; srv[s0 + 3] = p.w;
            }
        }
    }
    {
        const int l2 = (lane < 51) ? 2 * lane : 0;
        const int zr0 = w * 2, zr1 = w * 2 + 1;
        const int t0 = q * 16 + zr0;         // always <= tmax
        const int t1 = q * 16 + zr1;         // q3,w7: 63 -> invalid
        const int tc1 = (t1 <= tmax) ? t1 : tmax;
        float2 a0 = make_float2(0.f, 0.f);
        float2 a1 = make_float2(0.f, 0.f);
#pragma unroll 4
        for (int k = 0; k < 100; ++k) {
            const float2 wv = *(const float2*)&sM[k * 102 + l2];
            const float x0 = sT2[t0 * 102 + k];
            const float x1 = sT2[tc1 * 102 + k];
            a0.x += x0 * wv.x; a0.y += x0 * wv.y;
            a1.x += x1 * wv.x; a1.y += x1 * wv.y;
        }
        if (lane < 51) {
            *(float2*)&sZ[zr0 * 102 + l2] = a0;
            if (t1 <= tmax) *(float2*)&sZ[zr1 * 102 + l2] = a1;
        }
    }
    __syncthreads();

    // ---- P3: G own rows (2 per wave, lane = s) ----
    {
        const float kz = k0w[0];
        const int sc  = (lane <= tmax) ? lane : tmax;
        const int zr0 = w * 2, zr1 = w * 2 + 1;
        const int t1  = q * 16 + zr1;
        float g0 = kz + sZ[zr0 * 102 + 100] + srv[sc];
        float g1 = kz + sZ[zr1 * 102 + 100] + srv[sc];
#pragma unroll 5
        for (int k2 = 0; k2 < 50; ++k2) {
            const float2 tv = *(const float2*)&sT2[sc * 102 + 2 * k2];
            const float2 z0 = *(const float2*)&sZ[zr0 * 102 + 2 * k2];
            const float2 z1 = *(const float2*)&sZ[zr1 * 102 + 2 * k2];
            g0 += z0.x * tv.x + z0.y * tv.y;
            g1 += z1.x * tv.x + z1.y * tv.y;
        }
        if (lane <= tmax) {
            sG[zr0 * 64 + lane] = g0;
            if (t1 <= tmax) sG[zr1 * 64 + lane] = g1;
        }
    }
    __syncthreads();                 // T2/M33p/Z reads done; regions reusable

    // ---- P4: regs -> de (sT2 region), num (sM region); pure LDS writes ----
#pragma unroll
    for (int j = 0; j < 13; ++j) {
        const int i = tid + j * 512;
        if (i < srows * 100) {
            sT2[i] = rdd[j].x;        // de
            sM[i]  = rdd[j].y;        // num (becomes V in-place)
        }
    }
    __syncthreads();

    // ---- P5: 4-way chunked prefix over s (chunk c = tid>>7, d = tid&127) ----
    {
        const float av = Afl[8];
        const int c = tid >> 7;                  // wave-pair-uniform
        const int d = tid & 127;
        const int L = (srows + 3) >> 2;
        const int s0 = c * L;
        const int s1 = (s0 + L < srows) ? s0 + L : srows;
        if (d < 100) {                           // 5a: chunk totals -> sZ
            float Ts = 0.f;
            for (int s = s0; s < s1; ++s) Ts += sT2[s * 100 + d];
            sZ[c * 128 + d] = Ts;
        }
        __syncthreads();
        if (d < 100) {                           // 5b: carry + local prefix
            float D = 0.f;
            for (int cc = 0; cc < c; ++cc) D += sZ[cc * 128 + d];
            for (int s = s0; s < s1; ++s) {
                D += sT2[s * 100 + d];
                const float En = __expf(-av * D);
                sM[s * 100 + d] = sM[s * 100 + d] * En;          // V[s][d]
                const int zr = s - q * 16;
                if (zr >= 0) sM[6400 + zr * 100 + d] = __expf(av * D); // E
            }
        }
    }
    __syncthreads();

    // ---- P6: Y + head (2 t-rows per wave; in-wave reduce over d) ----
    {
        const int li = (lane < 50) ? lane : 49;
        const float4 mk = *(const float4*)&sMk[4 * li];
        float4 oc = make_float4(0.f, 0.f, 0.f, 0.f);
#pragma unroll
        for (int r = 0; r < 2; ++r) {
            const int zr = w * 2 + r;
            const int t  = q * 16 + zr;
            float o0 = 0.f, o1 = 0.f;
            if (t < SEQ) {
                float a0 = 0.f, a1 = 0.f;
                const int nf = (t + 1) >> 1;
                const float* gp = &sG[zr * 64];
                for (int s2 = 0; s2 < nf; ++s2) {
                    const float2 g2 = *(const float2*)&gp[2 * s2];
                    const float2 v0 = *(const float2*)&sM[(2 * s2) * 100 + 2 * li];
                    const float2 v1 = *(const float2*)&sM[(2 * s2 + 1) * 100 + 2 * li];
                    a0 += g2.x * v0.x + g2.y * v1.x;
                    a1 += g2.x * v0.y + g2.y * v1.y;
                }
                if ((t & 1) == 0) {        // even t: tail s = t
                    const float gg = gp[t];
                    const float2 vt = *(const float2*)&sM[t * 100 + 2 * li];
                    a0 += gg * vt.x; a1 += gg * vt.y;
                }
                const float2 e2 = *(const float2*)&sM[6400 + zr * 100 + 2 * li];
                const float y0 = (lane < 50) ? e2.x * a0 : 0.f;
                const float y1 = (lane < 50) ? e2.y * a1 : 0.f;
                o0 = y0 * mk.x + y1 * mk.z;
                o1 = y0 * mk.y + y1 * mk.w;
            }
            if (r == 0) { oc.x = o0; oc.y = o1; }
            else        { oc.z = o0; oc.w = o1; }
        }
        oc = waveReduceSum4(oc);
        if (lane == 0) {
            const float kv0 = sMk[200], kv1 = sMk[201];
#pragma unroll
            for (int r = 0; r < 2; ++r) {
                const int t = q * 16 + w * 2 + r;
                if (t >= SEQ) continue;
                const int row = b * SEQ + t;
                const float o0 = (r == 0 ? oc.x : oc.z) + kv0;
                const float o1 = (r == 0 ? oc.y : oc.w) + kv1;
                if (ISB) {
                    ((bf16*)outp)[row * 2 + 0] = __float2bfloat16(o0);
                    ((bf16*)outp)[row * 2 + 1] = __float2bfloat16(o1);
                } else {
                    *(float2*)((float*)outp + row * 2) = make_float2(o0, o1);
                }
            }
        }
    }
}

__global__ __launch_bounds__(512) void k_GYH(
    const float* __restrict__ t2g, const float* __restrict__ ddx,
    const float* __restrict__ M33p, const float* __restrict__ k0w,
    const float* __restrict__ Mkv, const float* __restrict__ Afl,
    void* __restrict__ outp, const unsigned short* __restrict__ probe)
{
    __shared__ __align__(16) float sT2[6426];    // T2[63][102]; then de[6300]
    __shared__ __align__(16) float sM[10240];    // M33p[100][102]; then V[63][100]@0 + E[16][100]@6400
    __shared__ __align__(16) float sZ[1632];     // Z own [16][102]; then chunk totals [4][128]
    __shared__ __align__(16) float sG[1024];     // G own [16][64]
    __shared__ __align__(16) float srv[64];
    __shared__ __align__(16) float sMk[204];
    if (!flags_uniform(Afl)) return;
    if (detect_bf16(probe))
        gyh_impl<true >(t2g, ddx, M33p, k0w, Mkv, Afl, outp, sT2, sM, sZ, sG, srv, sMk);
    else
        gyh_impl<false>(t2g, ddx, M33p, k0w, Mkv, Afl, outp, sT2, sM, sZ, sG, srv, sMk);
}

// ---------------------------------------------------------------------------
// Fallback kernels (gated off when A uniform): R9 k_B + k_scan (row-major y).
// ---------------------------------------------------------------------------
template<bool ISB>
__device__ __forceinline__ float4 LD4(const void* p, int i) {
    if (ISB) {
        const uint2 u = ((const uint2*)p)[i];
        float4 r;
        r.x = __uint_as_float(u.x << 16);
        r.y = __uint_as_float(u.x & 0xffff0000u);
        r.z = __uint_as_float(u.y << 16);
        r.w = __uint_as_float(u.y & 0xffff0000u);
        return r;
    } else return ((const float4*)p)[i];
}

template<bool ISB>
__device__ __forceinline__ void b_impl(
    const float* __restrict__ t2g,
    const void* __restrict__ sW2, const void* __restrict__ sb2,
    const void* __restrict__ sW3, const void* __restrict__ sb3,
    float* __restrict__ BC, float (&sT)[DM][8])
{
    const int t  = threadIdx.x;
    const int r0 = blockIdx.x * 8;
    if (t < DM) {
#pragma unroll
        for (int r = 0; r < 8; ++r) sT[t][r] = t2g[(r0 + r) * DM + t];
    }
    __syncthreads();
    const bool isB = t < 75;
    const bool valid = t < 150;
    const int colbase = isB ? 4 * t : (valid ? 4 * (t - 75) : 0);
    const void* Wp   = isB ? sW2 : sW3;
    const void* bias = isB ? sb2 : sb3;
    const int rs4 = NS >> 2;
    const int cb4 = colbase >> 2;
    float4 acc[8];
    {
        const float4 bv = LD4<ISB>(bias, cb4);
#pragma unroll
        for (int r = 0; r < 8; ++r) acc[r] = bv;
    }
    float4 ring[4];
#pragma unroll
    for (int j = 0; j < 4; ++j) ring[j] = LD4<ISB>(Wp, j * rs4 + cb4);
    for (int kk = 0; kk < DM; kk += 4) {
#pragma unroll
        for (int j = 0; j < 4; ++j) {
            const int k = kk + j;
            const float4 wv = ring[j];
            if (k + 4 < DM) ring[j] = LD4<ISB>(Wp, (k + 4) * rs4 + cb4);
            const float4 lo = *(const float4*)&sT[k][0];
            const float4 hi = *(const float4*)&sT[k][4];
            acc[0].x += lo.x * wv.x; acc[0].y += lo.x * wv.y; acc[0].z += lo.x * wv.z; acc[0].w += lo.x * wv.w;
            acc[1].x += lo.y * wv.x; acc[1].y += lo.y * wv.y; acc[1].z += lo.y * wv.z; acc[1].w += lo.y * wv.w;
            acc[2].x += lo.z * wv.x; acc[2].y += lo.z * wv.y; acc[2].z += lo.z * wv.z; acc[2].w += lo.z * wv.w;
            acc[3].x += lo.w * wv.x; acc[3].y += lo.w * wv.y; acc[3].z += lo.w * wv.z; acc[3].w += lo.w * wv.w;
            acc[4].x += hi.x * wv.x; acc[4].y += hi.x * wv.y; acc[4].z += hi.x * wv.z; acc[4].w += hi.x * wv.w;
            acc[5].x += hi.y * wv.x; acc[5].y += hi.y * wv.y; acc[5].z += hi.y * wv.z; acc[5].w += hi.y * wv.w;
            acc[6].x += hi.z * wv.x; acc[6].y += hi.z * wv.y; acc[6].z += hi.z * wv.z; acc[6].w += hi.z * wv.w;
            acc[7].x += hi.w * wv.x; acc[7].y += hi.w * wv.y; acc[7].z += hi.w * wv.z; acc[7].w += hi.w * wv.w;
        }
    }
    if (valid) {
        const int off = isB ? 0 : 1;
#pragma unroll
        for (int r = 0; r < 8; ++r) {
            float* bp = BC + (r0 + r) * (2 * NS) + 2 * colbase + off;
            bp[0] = acc[r].x; bp[2] = acc[r].y;
            bp[4] = acc[r].z; bp[6] = acc[r].w;
        }
    }
}

__global__ __launch_bounds__(192, 1) void k_B(
    const float* t2g, const void* sW2, const void* sb2,
    const void* sW3, const void* sb3, float* BC,
    const float* Afl, const unsigned short* probe)
{
    __shared__ __align__(16) float sT[DM][8];
    if (flags_uniform(Afl)) return;
    if (detect_bf16(probe)) b_impl<true >(t2g, sW2, sb2, sW3, sb3, BC, sT);
    else                    b_impl<false>(t2g, sW2, sb2, sW3, sb3, BC, sT);
}

template<bool ISB>
__device__ __forceinline__ void scan_impl(
    const float* __restrict__ ddx, const float* __restrict__ BC,
    const void* __restrict__ sA, float* __restrict__ y,
    float (&sacc)[4][16][2][68])
{
    const int w    = threadIdx.x >> 6;
    const int lane = threadIdx.x & 63;
    const int wid  = blockIdx.x * 4 + w;
    const int b    = wid / 50;
    const int dp   = wid % 50;
    const int d0   = 2 * dp, d1 = d0 + 1;

    int nc[5]; bool nv[5];
    float A0[5], A1[5], h0[5], h1[5];
#pragma unroll
    for (int c = 0; c < 5; ++c) {
        const int n = lane + 64 * c;
        nv[c] = n < NS;
        nc[c] = nv[c] ? n : 0;
        A0[c] = nv[c] ? LD<ISB>(sA, d0 * NS + nc[c]) : 0.f;
        A1[c] = nv[c] ? LD<ISB>(sA, d1 * NS + nc[c]) : 0.f;
        h0[c] = 0.f; h1[c] = 0.f;
    }
    const float* ddp = ddx + (b * SEQ) * (2 * DM) + 4 * dp;
    const float* BCp = BC  + (b * SEQ) * (2 * NS);
    float*       yp  = y   + (b * SEQ) * DM + d0;

    float4 pdd[3];
    float2 pbc[3][5];
#pragma unroll
    for (int j = 0; j < 3; ++j) {
        pdd[j] = *(const float4*)(ddp + j * (2 * DM));
#pragma unroll
        for (int c = 0; c < 5; ++c)
            pbc[j][c] = nv[c] ? *(const float2*)(BCp + j * (2 * NS) + 2 * nc[c])
                              : make_float2(0.f, 0.f);
    }
    const int pr = lane >> 1;
    const int hh = lane & 1;
    const int sa = pr & 15;
    const int aa = pr >> 4;

#pragma unroll 3
    for (int l = 0; l < SEQ; ++l) {
        const int bi = l % 3;
        const float4 dd = pdd[bi];
        float2 bc[5];
#pragma unroll
        for (int c = 0; c < 5; ++c) bc[c] = pbc[bi][c];
        if (l + 3 < SEQ) {
            pdd[bi] = *(const float4*)(ddp + (l + 3) * (2 * DM));
#pragma unroll
            for (int c = 0; c < 5; ++c)
                pbc[bi][c] = nv[c] ? *(const float2*)(BCp + (l + 3) * (2 * NS) + 2 * nc[c])
                                   : make_float2(0.f, 0.f);
        }
        float a0 = 0.f, a1 = 0.f;
#pragma unroll
        for (int c = 0; c < 5; ++c) {
            h0[c] = __expf(dd.x * A0[c]) * h0[c] + dd.y * bc[c].x;
            a0 += bc[c].y * h0[c];
            h1[c] = __expf(dd.z * A1[c]) * h1[c] + dd.w * bc[c].x;
            a1 += bc[c].y * h1[c];
        }
        const int s = l & 15;
        sacc[w][s][0][lane] = a0;
        sacc[w][s][1][lane] = a1;

        if (s == 15 || l == SEQ - 1) {
            const int l0 = l & ~15;
            const int cs = l - l0 + 1;
            float sum = 0.f;
            if (sa < cs) {
                const float* rowp = &sacc[w][sa][aa][hh * 32];
#pragma unroll
                for (int i = 0; i < 8; ++i) {
                    const float4 v = *(const float4*)(rowp + 4 * i);
                    sum += v.x + v.y + v.z + v.w;
                }
            }
            sum += __shfl_xor(sum, 1, 64);
            if (hh == 0 && sa < cs) yp[(l0 + sa) * DM + aa] = sum;
        }
    }
}

__global__ __launch_bounds__(256) void k_scan(
    const float* ddx, const float* BC, const void* sA, float* y,
    const float* Afl, const unsigned short* probe)
{
    __shared__ __align__(16) float sacc[4][16][2][68];
    if (flags_uniform(Afl)) return;
    if (detect_bf16(probe)) scan_impl<true >(ddx, BC, sA, y, sacc);
    else                    scan_impl<false>(ddx, BC, sA, y, sacc);
}

// ---------------------------------------------------------------------------
// k_headF: FALLBACK-only head. out[row] = y[row] @ M + k, row-major y.
// ---------------------------------------------------------------------------
template<bool ISB>
__device__ __forceinline__ void headf_impl(
    const float* __restrict__ y, const float* __restrict__ Mkv,
    void* __restrict__ outp)
{
    const int row = blockIdx.x * 256 + threadIdx.x;
    if (row >= ROWS) return;
    float a0 = Mkv[200], a1 = Mkv[201];
    const float* yr = y + row * DM;
#pragma unroll 4
    for (int k = 0; k < DM; ++k) {
        const float v = yr[k];
        const float2 m = *(const float2*)(Mkv + 2 * k);
        a0 += v * m.x;
        a1 += v * m.y;
    }
    if (ISB) {
        ((bf16*)outp)[row * 2 + 0] = __float2bfloat16(a0);
        ((bf16*)outp)[row * 2 + 1] = __float2bfloat16(a1);
    } else {
        *(float2*)((float*)outp + row * 2) = make_float2(a0, a1);
    }
}

__global__ __launch_bounds__(256) void k_headF(
    const float* y, const float* Mkv, void* outp,
    const float* Afl, const unsigned short* probe)
{
    if (flags_uniform(Afl)) return;
    if (detect_bf16(probe)) headf_impl<true >(y, Mkv, outp);
    else                    headf_impl<false>(y, Mkv, outp);
}

// ---------------------------------------------------------------------------
extern "C" void kernel_launch(void* const* d_in, const int* in_sizes, int n_in,
                              void* d_out, int out_size, void* d_ws, size_t ws_size,
                              hipStream_t stream)
{
    const void* text = d_in[0];
    const void* tW1  = d_in[3];
    const void* tb1  = d_in[4];
    const void* tg1  = d_in[5];
    const void* tbe1 = d_in[6];
    const void* tW2  = d_in[7];
    const void* tb2  = d_in[8];
    const void* tg2  = d_in[9];
    const void* tbe2 = d_in[10];
    const void* sW1  = d_in[11];
    const void* sb1  = d_in[12];
    const void* sW2  = d_in[13];
    const void* sb2  = d_in[14];
    const void* sW3  = d_in[15];
    const void* sb3  = d_in[16];
    const void* sA   = d_in[17];
    const void* cW1  = d_in[34];
    const void* cb1  = d_in[35];
    const void* cW2  = d_in[36];
    const void* cb2  = d_in[37];
    const unsigned short* probe = (const unsigned short*)d_in[3];

    float* ws   = (float*)d_ws;
    float* ddx  = ws;                         // ROWS*200
    float* BCv  = ddx + ROWS * 2 * DM;        // ROWS*600 (fallback BC)
    float* yv   = BCv + ROWS * 2 * NS;        // ROWS*100 (t2g; fallback y)
    float* Mkv  = yv + ROWS * DM;             // 202
    float* M33p = Mkv + 202;                  // 100*102
    float* k0w  = M33p + 10200;               // 1
    float* Afl  = k0w + 1;                    // 9 (8 flags + a)
    float* t2g  = yv;                         // alias: consumed before y write

    k_A<<<613, 256, 0, stream>>>(
        text, tW1, tb1, tg1, tbe1, tW2, tb2, tg2, tbe2,
        sW1, sb1, sW2, sb2, sW3, sb3, sA,
        cW1, cb1, cW2, cb2,
        ddx, t2g, Mkv, M33p, k0w, Afl, probe);

    // Fast path: fused G/V/E/Y/head, all-LDS inner loops, writes d_out.
    k_GYH<<<BATCH * 4, 512, 0, stream>>>(t2g, ddx, M33p, k0w, Mkv, Afl,
                                         d_out, probe);

    // Fallback path (gated off when A uniform):
    k_B<<<ROWS / 8, 192, 0, stream>>>(t2g, sW2, sb2, sW3, sb3, BCv, Afl, probe);
    k_scan<<<3200 / 4, 256, 0, stream>>>(ddx, BCv, sA, yv, Afl, probe);
    k_headF<<<(ROWS + 255) / 256, 256, 0, stream>>>(yv, Mkv, d_out, Afl, probe);
}